// Round 1
// baseline (2791.194 us; speedup 1.0000x reference)
//
#include <hip/hip_runtime.h>

#define NN 65536
#define EE 524288
#define EPX 589824   // EE + NN
#define GG 1024

// ---------------- CSR build ----------------

__launch_bounds__(256)
__global__ void k_deg(const int* __restrict__ dst0, const float* __restrict__ ea,
                      int* __restrict__ deg, float* __restrict__ mea)
{
    int e = blockIdx.x * 256 + threadIdx.x;
    if (e >= EE) return;
    int d = dst0[e];
    atomicAdd(&deg[d], 1);
    const float* ep = ea + (size_t)e * 12;
#pragma unroll
    for (int k = 0; k < 12; k++) atomicAdd(&mea[(size_t)d * 12 + k], ep[k]);
}

__launch_bounds__(256)
__global__ void k_meadiv(const int* __restrict__ deg, float* __restrict__ mea)
{
    int i = blockIdx.x * 256 + threadIdx.x;   // NN*12 threads
    int n = i / 12;
    float dv = fmaxf((float)deg[n], 1.0f);
    mea[i] = mea[i] / dv;
}

__launch_bounds__(1024)
__global__ void k_scan(const int* __restrict__ deg, int* __restrict__ rowptr)
{
    __shared__ int sums[1024];
    int t = threadIdx.x;
    int base = t * 64;
    int s = 0;
    for (int i = 0; i < 64; i++) s += deg[base + i] + 1;
    sums[t] = s;
    __syncthreads();
    for (int off = 1; off < 1024; off <<= 1) {
        int v = (t >= off) ? sums[t - off] : 0;
        __syncthreads();
        sums[t] += v;
        __syncthreads();
    }
    int off = sums[t] - s;   // exclusive prefix
    for (int i = 0; i < 64; i++) { rowptr[base + i] = off; off += deg[base + i] + 1; }
    if (t == 1023) rowptr[NN] = off;
}

__launch_bounds__(256)
__global__ void k_scatter(const int* __restrict__ src0, const int* __restrict__ dst0,
                          const int* __restrict__ rowptr, const int* __restrict__ deg,
                          int* __restrict__ fill, int* __restrict__ csr_src, int* __restrict__ csr_eid)
{
    int e = blockIdx.x * 256 + threadIdx.x;
    if (e >= EPX) return;
    if (e < EE) {
        int d = dst0[e];
        int pos = rowptr[d] + atomicAdd(&fill[d], 1);
        csr_src[pos] = src0[e];
        csr_eid[pos] = e;
    } else {
        int n = e - EE;
        int pos = rowptr[n] + deg[n];   // self-loop goes in the last slot
        csr_src[pos] = n;
        csr_eid[pos] = EE + n;
    }
}

// ---------------- input layer: h = relu(x @ Win + bin) ----------------

__launch_bounds__(256)
__global__ void k_input(const float* __restrict__ x, const float* __restrict__ Win,
                        const float* __restrict__ bin, float* __restrict__ h)
{
    __shared__ float W[21 * 128];
    int t = threadIdx.x;
    for (int i = t; i < 21 * 128; i += 256) W[i] = Win[i];
    __syncthreads();
    int c = t & 127, sub = t >> 7;
    int n0 = blockIdx.x * 16;
    float bc = bin[c];
    for (int i = 0; i < 8; i++) {
        int n = n0 + sub + i * 2;
        const float* xp = x + (size_t)n * 21;
        float acc = bc;
#pragma unroll
        for (int k = 0; k < 21; k++) acc = fmaf(xp[k], W[k * 128 + c], acc);
        h[(size_t)n * 128 + c] = fmaxf(acc, 0.f);
    }
}

// ---------------- GEMM: C[M,nc] = A[M,128] @ B[128,nc], 64x64 tiles ----------------

__launch_bounds__(256)
__global__ void k_gemm128(const float* __restrict__ A, const float* __restrict__ B, int ldb,
                          float* __restrict__ C, int ldc)
{
    __shared__ float As[64 * 132];
    __shared__ float Bs[128 * 68];
    int t = threadIdx.x;
    int rowBase = blockIdx.x * 64;
    int colBase = blockIdx.y * 64;
#pragma unroll
    for (int i = 0; i < 8; i++) {
        int f = i * 256 + t;
        int r = f >> 5, c4 = f & 31;
        float4 v = *reinterpret_cast<const float4*>(A + (size_t)(rowBase + r) * 128 + c4 * 4);
        *reinterpret_cast<float4*>(&As[r * 132 + c4 * 4]) = v;
    }
#pragma unroll
    for (int i = 0; i < 8; i++) {
        int f = i * 256 + t;
        int r = f >> 4, c4 = f & 15;
        float4 v = *reinterpret_cast<const float4*>(B + (size_t)r * ldb + colBase + c4 * 4);
        *reinterpret_cast<float4*>(&Bs[r * 68 + c4 * 4]) = v;
    }
    __syncthreads();
    int tx = t & 15, ty = t >> 4;
    float acc[4][4];
#pragma unroll
    for (int i = 0; i < 4; i++)
#pragma unroll
        for (int j = 0; j < 4; j++) acc[i][j] = 0.f;

    for (int k = 0; k < 128; k += 4) {
        float a[4][4], b[4][4];
#pragma unroll
        for (int i = 0; i < 4; i++)
            *reinterpret_cast<float4*>(&a[i][0]) =
                *reinterpret_cast<const float4*>(&As[(ty * 4 + i) * 132 + k]);
#pragma unroll
        for (int kk = 0; kk < 4; kk++)
            *reinterpret_cast<float4*>(&b[kk][0]) =
                *reinterpret_cast<const float4*>(&Bs[(k + kk) * 68 + tx * 4]);
#pragma unroll
        for (int kk = 0; kk < 4; kk++)
#pragma unroll
            for (int i = 0; i < 4; i++)
#pragma unroll
                for (int j = 0; j < 4; j++)
                    acc[i][j] = fmaf(a[i][kk], b[kk][j], acc[i][j]);
    }
#pragma unroll
    for (int i = 0; i < 4; i++) {
        float4 v; v.x = acc[i][0]; v.y = acc[i][1]; v.z = acc[i][2]; v.w = acc[i][3];
        *reinterpret_cast<float4*>(C + (size_t)(rowBase + ty * 4 + i) * ldc + colBase + tx * 4) = v;
    }
}

// ---------------- GATv2 edge aggregation: one wave per dst node ----------------
// lane l owns features f0=2l, f0+1 (head = l>>4); online softmax per head.

__launch_bounds__(256)
__global__ void k_gat(const float* __restrict__ xl, const float* __restrict__ xr,
                      const float* __restrict__ eattr, const float* __restrict__ mea,
                      const int* __restrict__ rowptr, const int* __restrict__ csr_src,
                      const int* __restrict__ csr_eid,
                      const float* __restrict__ We, const float* __restrict__ att,
                      const float* __restrict__ bconv, float* __restrict__ g)
{
    int wave = threadIdx.x >> 6, lane = threadIdx.x & 63;
    int n = blockIdx.x * 4 + wave;
    int f0 = lane * 2;

    float wex[12], wey[12];
#pragma unroll
    for (int k = 0; k < 12; k++) {
        float2 w = *reinterpret_cast<const float2*>(We + k * 128 + f0);
        wex[k] = w.x; wey[k] = w.y;
    }
    float2 av  = *reinterpret_cast<const float2*>(att + f0);
    float2 xrv = *reinterpret_cast<const float2*>(xr + (size_t)n * 128 + f0);

    float m = -INFINITY, s = 0.f, a0 = 0.f, a1 = 0.f;
    int beg = rowptr[n], end = rowptr[n + 1];
    for (int idx = beg; idx < end; ++idx) {
        int src = csr_src[idx];
        int eid = csr_eid[idx];
        const float* ep = (eid < EE) ? (eattr + (size_t)eid * 12)
                                     : (mea + (size_t)(eid - EE) * 12);
        float4 e0 = *reinterpret_cast<const float4*>(ep);
        float4 e1 = *reinterpret_cast<const float4*>(ep + 4);
        float4 e2 = *reinterpret_cast<const float4*>(ep + 8);
        float2 xlv = *reinterpret_cast<const float2*>(xl + (size_t)src * 128 + f0);

        float el0 = e0.x * wex[0] + e0.y * wex[1] + e0.z * wex[2]  + e0.w * wex[3]
                  + e1.x * wex[4] + e1.y * wex[5] + e1.z * wex[6]  + e1.w * wex[7]
                  + e2.x * wex[8] + e2.y * wex[9] + e2.z * wex[10] + e2.w * wex[11];
        float el1 = e0.x * wey[0] + e0.y * wey[1] + e0.z * wey[2]  + e0.w * wey[3]
                  + e1.x * wey[4] + e1.y * wey[5] + e1.z * wey[6]  + e1.w * wey[7]
                  + e2.x * wey[8] + e2.y * wey[9] + e2.z * wey[10] + e2.w * wey[11];

        float m0 = xlv.x + xrv.x + el0;
        float m1 = xlv.y + xrv.y + el1;
        float v0 = (m0 > 0.f) ? m0 : 0.2f * m0;
        float v1 = (m1 > 0.f) ? m1 : 0.2f * m1;
        float tt = v0 * av.x + v1 * av.y;
        tt += __shfl_xor(tt, 1);
        tt += __shfl_xor(tt, 2);
        tt += __shfl_xor(tt, 4);
        tt += __shfl_xor(tt, 8);   // per-head logit, broadcast to the 16-lane head group

        float nm = fmaxf(m, tt);
        float so = __expf(m - nm);
        float w  = __expf(tt - nm);
        s  = s * so + w;
        a0 = a0 * so + w * xlv.x;
        a1 = a1 * so + w * xlv.y;
        m = nm;
    }
    float inv = 1.f / s;   // s > 0 guaranteed by the self-loop
    float2 bc = *reinterpret_cast<const float2*>(bconv + f0);
    float2 r; r.x = a0 * inv + bc.x; r.y = a1 * inv + bc.y;
    *reinterpret_cast<float2*>(g + (size_t)n * 128 + f0) = r;
}

// ---------------- BatchNorm ----------------

__launch_bounds__(256)
__global__ void k_bnstats(const float* __restrict__ X, float* __restrict__ sum, float* __restrict__ sq)
{
    int col = threadIdx.x & 127;
    int half = threadIdx.x >> 7;
    int rbase = blockIdx.x * 256 + half;
    float s = 0.f, q = 0.f;
    for (int i = 0; i < 128; i++) {
        float v = X[(size_t)(rbase + i * 2) * 128 + col];
        s += v; q += v * v;
    }
    __shared__ float ls[256], lq[256];
    ls[threadIdx.x] = s; lq[threadIdx.x] = q;
    __syncthreads();
    if (half == 0) {
        s += ls[threadIdx.x + 128];
        q += lq[threadIdx.x + 128];
        atomicAdd(&sum[col], s);
        atomicAdd(&sq[col], q);
    }
}

__launch_bounds__(128)
__global__ void k_bnfinal(const float* __restrict__ sum, const float* __restrict__ sq,
                          const float* __restrict__ scale, const float* __restrict__ bias,
                          float* __restrict__ sA, float* __restrict__ bA)
{
    int c = threadIdx.x;
    const float invN = 1.0f / (float)NN;
    float mean = sum[c] * invN;
    float var  = sq[c] * invN - mean * mean;
    float sc   = scale[c] * rsqrtf(var + 1e-5f);
    sA[c] = sc;
    bA[c] = bias[c] - mean * sc;
}

__launch_bounds__(256)
__global__ void k_bnapply_relu(const float4* __restrict__ gin, const float* __restrict__ sA,
                               const float* __restrict__ bA, float4* __restrict__ out)
{
    int idx = blockIdx.x * 256 + threadIdx.x;   // NN*128/4 threads
    int c4 = (idx & 31) * 4;
    float4 v = gin[idx];
    float4 r;
    r.x = fmaxf(fmaf(v.x, sA[c4 + 0], bA[c4 + 0]), 0.f);
    r.y = fmaxf(fmaf(v.y, sA[c4 + 1], bA[c4 + 1]), 0.f);
    r.z = fmaxf(fmaf(v.z, sA[c4 + 2], bA[c4 + 2]), 0.f);
    r.w = fmaxf(fmaf(v.w, sA[c4 + 3], bA[c4 + 3]), 0.f);
    out[idx] = r;
}

__launch_bounds__(256)
__global__ void k_bnapply_res_relu(const float4* __restrict__ gin, const float* __restrict__ sA,
                                   const float* __restrict__ bA, float4* __restrict__ hbuf)
{
    int idx = blockIdx.x * 256 + threadIdx.x;
    int c4 = (idx & 31) * 4;
    float4 v = gin[idx];
    float4 hv = hbuf[idx];
    float4 r;
    r.x = fmaxf(fmaf(v.x, sA[c4 + 0], bA[c4 + 0]) + hv.x, 0.f);
    r.y = fmaxf(fmaf(v.y, sA[c4 + 1], bA[c4 + 1]) + hv.y, 0.f);
    r.z = fmaxf(fmaf(v.z, sA[c4 + 2], bA[c4 + 2]) + hv.z, 0.f);
    r.w = fmaxf(fmaf(v.w, sA[c4 + 3], bA[c4 + 3]) + hv.w, 0.f);
    hbuf[idx] = r;
}

// ---------------- pooling + value head ----------------

__launch_bounds__(256)
__global__ void k_pool(const float* __restrict__ h, const int* __restrict__ batch,
                       float* __restrict__ pooled, float* __restrict__ cnt)
{
    int idx = blockIdx.x * 256 + threadIdx.x;   // NN*32 threads
    int n = idx >> 5, q = idx & 31;
    int b = batch[n];
    float4 v = *reinterpret_cast<const float4*>(h + (size_t)n * 128 + q * 4);
    atomicAdd(&pooled[(size_t)b * 128 + q * 4 + 0], v.x);
    atomicAdd(&pooled[(size_t)b * 128 + q * 4 + 1], v.y);
    atomicAdd(&pooled[(size_t)b * 128 + q * 4 + 2], v.z);
    atomicAdd(&pooled[(size_t)b * 128 + q * 4 + 3], v.w);
    if (q == 0) atomicAdd(&cnt[b], 1.0f);
}

__launch_bounds__(64)
__global__ void k_value(const float* __restrict__ pooled, const float* __restrict__ cnt,
                        const float* __restrict__ Wv1, const float* __restrict__ bv1,
                        const float* __restrict__ Wv2, const float* __restrict__ bv2,
                        float* __restrict__ out)
{
    int gi = blockIdx.x;
    int l = threadIdx.x;
    float inv = 1.f / fmaxf(cnt[gi], 1.f);
    const float* pr = pooled + (size_t)gi * 128;
    float z = bv1[l];
    for (int k = 0; k < 128; k++) z = fmaf(pr[k] * inv, Wv1[k * 64 + l], z);
    z = fmaxf(z, 0.f);
#pragma unroll
    for (int j = 0; j < 3; j++) {
        float p = z * Wv2[l * 3 + j];
        p += __shfl_xor(p, 32); p += __shfl_xor(p, 16); p += __shfl_xor(p, 8);
        p += __shfl_xor(p, 4);  p += __shfl_xor(p, 2);  p += __shfl_xor(p, 1);
        if (l == 0) out[gi * 3 + j] = p + bv2[j];
    }
}

// ---------------- policy head ----------------
// policy[e] = relu(P1[src] + P2[dst] + ea@Wp1c + bp1) . Wp2 + bp2

__launch_bounds__(256)
__global__ void k_policy(const float* __restrict__ P1, const float* __restrict__ P2,
                         const float* __restrict__ eattr,
                         const int* __restrict__ src0, const int* __restrict__ dst0,
                         const float* __restrict__ Wp1c, const float* __restrict__ bp1,
                         const float* __restrict__ Wp2, const float* __restrict__ bp2,
                         float* __restrict__ out)
{
    int wave = (blockIdx.x * 256 + threadIdx.x) >> 6;   // 65536 waves
    int lane = threadIdx.x & 63;
    float w1c[12];
#pragma unroll
    for (int k = 0; k < 12; k++) w1c[k] = Wp1c[k * 64 + lane];
    float wp2 = Wp2[lane];
    float bb = bp1[lane];
    float b2 = bp2[0];
    for (int i = 0; i < 8; i++) {
        int e = wave * 8 + i;
        int sI = src0[e], dI = dst0[e];
        const float* ep = eattr + (size_t)e * 12;
        float4 e0 = *reinterpret_cast<const float4*>(ep);
        float4 e1 = *reinterpret_cast<const float4*>(ep + 4);
        float4 e2 = *reinterpret_cast<const float4*>(ep + 8);
        float z = P1[(size_t)sI * 64 + lane] + P2[(size_t)dI * 64 + lane] + bb;
        z += e0.x * w1c[0] + e0.y * w1c[1] + e0.z * w1c[2]  + e0.w * w1c[3]
           + e1.x * w1c[4] + e1.y * w1c[5] + e1.z * w1c[6]  + e1.w * w1c[7]
           + e2.x * w1c[8] + e2.y * w1c[9] + e2.z * w1c[10] + e2.w * w1c[11];
        z = fmaxf(z, 0.f);
        float p = z * wp2;
        p += __shfl_xor(p, 32); p += __shfl_xor(p, 16); p += __shfl_xor(p, 8);
        p += __shfl_xor(p, 4);  p += __shfl_xor(p, 2);  p += __shfl_xor(p, 1);
        if (lane == 0) out[3072 + e] = p + b2;
    }
}

// ---------------- host ----------------

extern "C" void kernel_launch(void* const* d_in, const int* in_sizes, int n_in,
                              void* d_out, int out_size, void* d_ws, size_t ws_size,
                              hipStream_t stream)
{
    const float* x     = (const float*)d_in[0];
    const float* eattr = (const float*)d_in[1];
    const int*   eidx  = (const int*)d_in[2];
    const int*   batch = (const int*)d_in[3];
    const float* Win   = (const float*)d_in[4];
    const float* bin   = (const float*)d_in[5];
    const float* Wl    = (const float*)d_in[6];
    const float* Wr    = (const float*)d_in[7];
    const float* We    = (const float*)d_in[8];
    const float* att   = (const float*)d_in[9];
    const float* bconv = (const float*)d_in[10];
    const float* bnsc  = (const float*)d_in[11];
    const float* bnbi  = (const float*)d_in[12];
    const float* Wv1   = (const float*)d_in[13];
    const float* bv1   = (const float*)d_in[14];
    const float* Wv2   = (const float*)d_in[15];
    const float* bv2   = (const float*)d_in[16];
    const float* Wp1   = (const float*)d_in[17];
    const float* bp1   = (const float*)d_in[18];
    const float* Wp2   = (const float*)d_in[19];
    const float* bp2   = (const float*)d_in[20];
    float* out = (float*)d_out;

    const int* src0 = eidx;
    const int* dst0 = eidx + EE;

    const size_t NH = (size_t)NN * 128;
    float* ws   = (float*)d_ws;
    float* h    = ws;               // N*128
    float* h1   = h + NH;
    float* g    = h1 + NH;
    float* xl   = g + NH;           // reused as P1 for policy head
    float* xr   = xl + NH;          // reused as P2
    float* mea  = xr + NH;          // N*12
    int* rowptr = (int*)(mea + (size_t)NN * 12);   // N+1
    int* deg    = rowptr + (NN + 1);
    int* fill   = deg + NN;
    int* csr_src= fill + NN;        // EPX
    int* csr_eid= csr_src + EPX;    // EPX
    float* bnsum = (float*)(csr_eid + EPX);  // 128
    float* bnsq  = bnsum + 128;
    float* sA    = bnsq + 128;
    float* bA    = sA + 128;
    float* pooled= bA + 128;        // G*128
    float* cnt   = pooled + (size_t)GG * 128;  // G

    // zero mea + rowptr + deg + fill (contiguous)
    hipMemsetAsync(mea, 0, ((size_t)NN * 12 + (NN + 1) + NN + NN) * sizeof(float), stream);

    // CSR build
    k_deg<<<EE / 256, 256, 0, stream>>>(dst0, eattr, deg, mea);
    k_meadiv<<<(NN * 12) / 256, 256, 0, stream>>>(deg, mea);
    k_scan<<<1, 1024, 0, stream>>>(deg, rowptr);
    k_scatter<<<EPX / 256, 256, 0, stream>>>(src0, dst0, rowptr, deg, fill, csr_src, csr_eid);

    // input layer
    k_input<<<NN / 16, 256, 0, stream>>>(x, Win, bin, h);

    // 8 GATv2 + BN layers
    for (int l = 0; l < 8; l++) {
        const float* hin = (l % 2 == 0) ? h : h1;
        k_gemm128<<<dim3(NN / 64, 2), 256, 0, stream>>>(hin, Wl + (size_t)l * 16384, 128, xl, 128);
        k_gemm128<<<dim3(NN / 64, 2), 256, 0, stream>>>(hin, Wr + (size_t)l * 16384, 128, xr, 128);
        k_gat<<<NN / 4, 256, 0, stream>>>(xl, xr, eattr, mea, rowptr, csr_src, csr_eid,
                                          We + (size_t)l * 1536, att + (size_t)l * 128,
                                          bconv + (size_t)l * 128, g);
        hipMemsetAsync(bnsum, 0, 2 * 128 * sizeof(float), stream);
        k_bnstats<<<256, 256, 0, stream>>>(g, bnsum, bnsq);
        k_bnfinal<<<1, 128, 0, stream>>>(bnsum, bnsq, bnsc + (size_t)l * 128, bnbi + (size_t)l * 128, sA, bA);
        if (l % 2 == 0)
            k_bnapply_relu<<<(NN * 128 / 4) / 256, 256, 0, stream>>>((const float4*)g, sA, bA, (float4*)h1);
        else
            k_bnapply_res_relu<<<(NN * 128 / 4) / 256, 256, 0, stream>>>((const float4*)g, sA, bA, (float4*)h);
    }

    // pooling + value head
    hipMemsetAsync(pooled, 0, ((size_t)GG * 128 + GG) * sizeof(float), stream);
    k_pool<<<(NN * 32) / 256, 256, 0, stream>>>(h, batch, pooled, cnt);
    k_value<<<GG, 64, 0, stream>>>(pooled, cnt, Wv1, bv1, Wv2, bv2, out);

    // policy head: P1 = h @ Wp1[0:128], P2 = h @ Wp1[128:256]
    k_gemm128<<<dim3(NN / 64, 1), 256, 0, stream>>>(h, Wp1, 64, xl, 64);
    k_gemm128<<<dim3(NN / 64, 1), 256, 0, stream>>>(h, Wp1 + 128 * 64, 64, xr, 64);
    k_policy<<<(NN) / 4, 256, 0, stream>>>(xl, xr, eattr, src0, dst0,
                                           Wp1 + 256 * 64, bp1, Wp2, bp2, out);
}

// Round 2
// 2414.312 us; speedup vs baseline: 1.1561x; 1.1561x over previous
//
#include <hip/hip_runtime.h>

#define NN 65536
#define EE 524288
#define EPX 589824   // EE + NN
#define GG 1024

// ---------------- CSR build ----------------

__launch_bounds__(256)
__global__ void k_deg(const int* __restrict__ dst0, int* __restrict__ deg)
{
    int e = blockIdx.x * 256 + threadIdx.x;
    if (e >= EE) return;
    atomicAdd(&deg[dst0[e]], 1);
}

__launch_bounds__(1024)
__global__ void k_scan(const int* __restrict__ deg, int* __restrict__ rowptr)
{
    __shared__ int sums[1024];
    int t = threadIdx.x;
    int base = t * 64;
    int s = 0;
    for (int i = 0; i < 64; i++) s += deg[base + i] + 1;
    sums[t] = s;
    __syncthreads();
    for (int off = 1; off < 1024; off <<= 1) {
        int v = (t >= off) ? sums[t - off] : 0;
        __syncthreads();
        sums[t] += v;
        __syncthreads();
    }
    int off = sums[t] - s;   // exclusive prefix
    for (int i = 0; i < 64; i++) { rowptr[base + i] = off; off += deg[base + i] + 1; }
    if (t == 1023) rowptr[NN] = off;
}

__launch_bounds__(256)
__global__ void k_scatter(const int* __restrict__ src0, const int* __restrict__ dst0,
                          const int* __restrict__ rowptr, const int* __restrict__ deg,
                          int* __restrict__ fill, int* __restrict__ csr_src, int* __restrict__ csr_eid)
{
    int e = blockIdx.x * 256 + threadIdx.x;
    if (e >= EPX) return;
    if (e < EE) {
        int d = dst0[e];
        int pos = rowptr[d] + atomicAdd(&fill[d], 1);
        csr_src[pos] = src0[e];
        csr_eid[pos] = e;
    } else {
        int n = e - EE;
        int pos = rowptr[n] + deg[n];   // self-loop goes in the last slot
        csr_src[pos] = n;
        csr_eid[pos] = EE + n;
    }
}

// mean edge attr per node, CSR-based (no atomics). 16 threads per node, lanes 0..11 active.
__launch_bounds__(256)
__global__ void k_mea(const int* __restrict__ rowptr, const int* __restrict__ csr_eid,
                      const float* __restrict__ eattr, float* __restrict__ mea)
{
    int tid = blockIdx.x * 256 + threadIdx.x;   // NN*16 threads
    int n = tid >> 4;
    int lk = tid & 15;
    int beg = rowptr[n], end = rowptr[n + 1] - 1;   // exclude self-loop (last slot)
    float s = 0.f;
    for (int p = beg; p < end; ++p) {
        int eid = csr_eid[p];
        if (lk < 12) s += eattr[(size_t)eid * 12 + lk];
    }
    if (lk < 12) {
        float dv = fmaxf((float)(end - beg), 1.0f);
        mea[(size_t)n * 12 + lk] = s / dv;
    }
}

// ---------------- input layer: h = relu(x @ Win + bin) ----------------

__launch_bounds__(256)
__global__ void k_input(const float* __restrict__ x, const float* __restrict__ Win,
                        const float* __restrict__ bin, float* __restrict__ h)
{
    __shared__ float W[21 * 128];
    int t = threadIdx.x;
    for (int i = t; i < 21 * 128; i += 256) W[i] = Win[i];
    __syncthreads();
    int c = t & 127, sub = t >> 7;
    int n0 = blockIdx.x * 16;
    float bc = bin[c];
    for (int i = 0; i < 8; i++) {
        int n = n0 + sub + i * 2;
        const float* xp = x + (size_t)n * 21;
        float acc = bc;
#pragma unroll
        for (int k = 0; k < 21; k++) acc = fmaf(xp[k], W[k * 128 + c], acc);
        h[(size_t)n * 128 + c] = fmaxf(acc, 0.f);
    }
}

// ---------------- GEMM: C[M,64tile] = A[M,128] @ B[128,64tile] ----------------

__device__ __forceinline__ void gemm_body(const float* __restrict__ A, const float* __restrict__ B,
                                          int ldb, float* __restrict__ C, int ldc,
                                          int rowBase, int colBase)
{
    __shared__ float As[64 * 132];
    __shared__ float Bs[128 * 68];
    int t = threadIdx.x;
#pragma unroll
    for (int i = 0; i < 8; i++) {
        int f = i * 256 + t;
        int r = f >> 5, c4 = f & 31;
        float4 v = *reinterpret_cast<const float4*>(A + (size_t)(rowBase + r) * 128 + c4 * 4);
        *reinterpret_cast<float4*>(&As[r * 132 + c4 * 4]) = v;
    }
#pragma unroll
    for (int i = 0; i < 8; i++) {
        int f = i * 256 + t;
        int r = f >> 4, c4 = f & 15;
        float4 v = *reinterpret_cast<const float4*>(B + (size_t)r * ldb + colBase + c4 * 4);
        *reinterpret_cast<float4*>(&Bs[r * 68 + c4 * 4]) = v;
    }
    __syncthreads();
    int tx = t & 15, ty = t >> 4;
    float acc[4][4];
#pragma unroll
    for (int i = 0; i < 4; i++)
#pragma unroll
        for (int j = 0; j < 4; j++) acc[i][j] = 0.f;

    for (int k = 0; k < 128; k += 4) {
        float a[4][4], b[4][4];
#pragma unroll
        for (int i = 0; i < 4; i++)
            *reinterpret_cast<float4*>(&a[i][0]) =
                *reinterpret_cast<const float4*>(&As[(ty * 4 + i) * 132 + k]);
#pragma unroll
        for (int kk = 0; kk < 4; kk++)
            *reinterpret_cast<float4*>(&b[kk][0]) =
                *reinterpret_cast<const float4*>(&Bs[(k + kk) * 68 + tx * 4]);
#pragma unroll
        for (int kk = 0; kk < 4; kk++)
#pragma unroll
            for (int i = 0; i < 4; i++)
#pragma unroll
                for (int j = 0; j < 4; j++)
                    acc[i][j] = fmaf(a[i][kk], b[kk][j], acc[i][j]);
    }
#pragma unroll
    for (int i = 0; i < 4; i++) {
        float4 v; v.x = acc[i][0]; v.y = acc[i][1]; v.z = acc[i][2]; v.w = acc[i][3];
        *reinterpret_cast<float4*>(C + (size_t)(rowBase + ty * 4 + i) * ldc + colBase + tx * 4) = v;
    }
}

// xl and xr in one dispatch: grid.y 0..3 (y<2 -> xl cols 0/64; y>=2 -> xr)
__launch_bounds__(256)
__global__ void k_gemm_xlxr(const float* __restrict__ A, const float* __restrict__ Bl,
                            const float* __restrict__ Br, float* __restrict__ Cl,
                            float* __restrict__ Cr)
{
    int yb = blockIdx.y;
    const float* B = (yb < 2) ? Bl : Br;
    float* C = (yb < 2) ? Cl : Cr;
    gemm_body(A, B, 128, C, 128, blockIdx.x * 64, (yb & 1) * 64);
}

__launch_bounds__(256)
__global__ void k_gemm64(const float* __restrict__ A, const float* __restrict__ B,
                         float* __restrict__ C)
{
    gemm_body(A, B, 64, C, 64, blockIdx.x * 64, 0);
}

// ---------------- GATv2 edge aggregation: one wave per dst node ----------------
// lane l owns features f0=2l, f0+1 (head = l>>4); online softmax per head; 2-edge unroll.

__launch_bounds__(256)
__global__ void k_gat(const float* __restrict__ xl, const float* __restrict__ xr,
                      const float* __restrict__ eattr, const float* __restrict__ mea,
                      const int* __restrict__ rowptr, const int* __restrict__ csr_src,
                      const int* __restrict__ csr_eid,
                      const float* __restrict__ We, const float* __restrict__ att,
                      const float* __restrict__ bconv, float* __restrict__ g)
{
    int wave = threadIdx.x >> 6, lane = threadIdx.x & 63;
    int n = blockIdx.x * 4 + wave;
    int f0 = lane * 2;

    float wex[12], wey[12];
#pragma unroll
    for (int k = 0; k < 12; k++) {
        float2 w = *reinterpret_cast<const float2*>(We + k * 128 + f0);
        wex[k] = w.x; wey[k] = w.y;
    }
    float2 av  = *reinterpret_cast<const float2*>(att + f0);
    float2 xrv = *reinterpret_cast<const float2*>(xr + (size_t)n * 128 + f0);

    float m = -INFINITY, s = 0.f, a0 = 0.f, a1 = 0.f;
    int beg = rowptr[n], end = rowptr[n + 1];
    int idx = beg;
    for (; idx + 2 <= end; idx += 2) {
        int s0 = csr_src[idx],  s1 = csr_src[idx + 1];
        int i0 = csr_eid[idx],  i1 = csr_eid[idx + 1];
        const float* p0 = (i0 < EE) ? (eattr + (size_t)i0 * 12) : (mea + (size_t)(i0 - EE) * 12);
        const float* p1 = (i1 < EE) ? (eattr + (size_t)i1 * 12) : (mea + (size_t)(i1 - EE) * 12);
        float4 a0v = *reinterpret_cast<const float4*>(p0);
        float4 a1v = *reinterpret_cast<const float4*>(p0 + 4);
        float4 a2v = *reinterpret_cast<const float4*>(p0 + 8);
        float4 b0v = *reinterpret_cast<const float4*>(p1);
        float4 b1v = *reinterpret_cast<const float4*>(p1 + 4);
        float4 b2v = *reinterpret_cast<const float4*>(p1 + 8);
        float2 xa = *reinterpret_cast<const float2*>(xl + (size_t)s0 * 128 + f0);
        float2 xb = *reinterpret_cast<const float2*>(xl + (size_t)s1 * 128 + f0);

        float ex0 = a0v.x*wex[0]+a0v.y*wex[1]+a0v.z*wex[2] +a0v.w*wex[3]
                  + a1v.x*wex[4]+a1v.y*wex[5]+a1v.z*wex[6] +a1v.w*wex[7]
                  + a2v.x*wex[8]+a2v.y*wex[9]+a2v.z*wex[10]+a2v.w*wex[11];
        float ey0 = a0v.x*wey[0]+a0v.y*wey[1]+a0v.z*wey[2] +a0v.w*wey[3]
                  + a1v.x*wey[4]+a1v.y*wey[5]+a1v.z*wey[6] +a1v.w*wey[7]
                  + a2v.x*wey[8]+a2v.y*wey[9]+a2v.z*wey[10]+a2v.w*wey[11];
        float ex1 = b0v.x*wex[0]+b0v.y*wex[1]+b0v.z*wex[2] +b0v.w*wex[3]
                  + b1v.x*wex[4]+b1v.y*wex[5]+b1v.z*wex[6] +b1v.w*wex[7]
                  + b2v.x*wex[8]+b2v.y*wex[9]+b2v.z*wex[10]+b2v.w*wex[11];
        float ey1 = b0v.x*wey[0]+b0v.y*wey[1]+b0v.z*wey[2] +b0v.w*wey[3]
                  + b1v.x*wey[4]+b1v.y*wey[5]+b1v.z*wey[6] +b1v.w*wey[7]
                  + b2v.x*wey[8]+b2v.y*wey[9]+b2v.z*wey[10]+b2v.w*wey[11];

        float m00 = xa.x + xrv.x + ex0, m01 = xa.y + xrv.y + ey0;
        float m10 = xb.x + xrv.x + ex1, m11 = xb.y + xrv.y + ey1;
        float v00 = (m00 > 0.f) ? m00 : 0.2f * m00;
        float v01 = (m01 > 0.f) ? m01 : 0.2f * m01;
        float v10 = (m10 > 0.f) ? m10 : 0.2f * m10;
        float v11 = (m11 > 0.f) ? m11 : 0.2f * m11;
        float t0 = v00 * av.x + v01 * av.y;
        float t1 = v10 * av.x + v11 * av.y;
        t0 += __shfl_xor(t0, 1);  t1 += __shfl_xor(t1, 1);
        t0 += __shfl_xor(t0, 2);  t1 += __shfl_xor(t1, 2);
        t0 += __shfl_xor(t0, 4);  t1 += __shfl_xor(t1, 4);
        t0 += __shfl_xor(t0, 8);  t1 += __shfl_xor(t1, 8);

        float nm = fmaxf(m, fmaxf(t0, t1));
        float so = __expf(m - nm);
        float w0 = __expf(t0 - nm);
        float w1 = __expf(t1 - nm);
        s  = s * so + w0 + w1;
        a0 = a0 * so + w0 * xa.x + w1 * xb.x;
        a1 = a1 * so + w0 * xa.y + w1 * xb.y;
        m = nm;
    }
    if (idx < end) {
        int src = csr_src[idx];
        int eid = csr_eid[idx];
        const float* ep = (eid < EE) ? (eattr + (size_t)eid * 12) : (mea + (size_t)(eid - EE) * 12);
        float4 e0 = *reinterpret_cast<const float4*>(ep);
        float4 e1 = *reinterpret_cast<const float4*>(ep + 4);
        float4 e2 = *reinterpret_cast<const float4*>(ep + 8);
        float2 xlv = *reinterpret_cast<const float2*>(xl + (size_t)src * 128 + f0);
        float el0 = e0.x*wex[0]+e0.y*wex[1]+e0.z*wex[2] +e0.w*wex[3]
                  + e1.x*wex[4]+e1.y*wex[5]+e1.z*wex[6] +e1.w*wex[7]
                  + e2.x*wex[8]+e2.y*wex[9]+e2.z*wex[10]+e2.w*wex[11];
        float el1 = e0.x*wey[0]+e0.y*wey[1]+e0.z*wey[2] +e0.w*wey[3]
                  + e1.x*wey[4]+e1.y*wey[5]+e1.z*wey[6] +e1.w*wey[7]
                  + e2.x*wey[8]+e2.y*wey[9]+e2.z*wey[10]+e2.w*wey[11];
        float m0 = xlv.x + xrv.x + el0;
        float m1 = xlv.y + xrv.y + el1;
        float v0 = (m0 > 0.f) ? m0 : 0.2f * m0;
        float v1 = (m1 > 0.f) ? m1 : 0.2f * m1;
        float tt = v0 * av.x + v1 * av.y;
        tt += __shfl_xor(tt, 1);
        tt += __shfl_xor(tt, 2);
        tt += __shfl_xor(tt, 4);
        tt += __shfl_xor(tt, 8);
        float nm = fmaxf(m, tt);
        float so = __expf(m - nm);
        float w  = __expf(tt - nm);
        s  = s * so + w;
        a0 = a0 * so + w * xlv.x;
        a1 = a1 * so + w * xlv.y;
        m = nm;
    }
    float inv = 1.f / s;   // s > 0 guaranteed by the self-loop
    float2 bc = *reinterpret_cast<const float2*>(bconv + f0);
    float2 r; r.x = a0 * inv + bc.x; r.y = a1 * inv + bc.y;
    *reinterpret_cast<float2*>(g + (size_t)n * 128 + f0) = r;
}

// ---------------- BatchNorm ----------------

__launch_bounds__(256)
__global__ void k_bnstats(const float* __restrict__ X, float* __restrict__ sum, float* __restrict__ sq)
{
    int col = threadIdx.x & 127;
    int half = threadIdx.x >> 7;
    int rbase = blockIdx.x * 256 + half;
    float s = 0.f, q = 0.f;
    for (int i = 0; i < 128; i++) {
        float v = X[(size_t)(rbase + i * 2) * 128 + col];
        s += v; q += v * v;
    }
    __shared__ float ls[256], lq[256];
    ls[threadIdx.x] = s; lq[threadIdx.x] = q;
    __syncthreads();
    if (half == 0) {
        s += ls[threadIdx.x + 128];
        q += lq[threadIdx.x + 128];
        atomicAdd(&sum[col], s);
        atomicAdd(&sq[col], q);
    }
}

__device__ __forceinline__ void bn_coeffs(const float* __restrict__ bnsum, const float* __restrict__ bnsq,
                                          const float* __restrict__ scale, const float* __restrict__ bias,
                                          float* sA, float* bA)
{
    int t = threadIdx.x;
    if (t < 128) {
        const float invN = 1.0f / (float)NN;
        float mean = bnsum[t] * invN;
        float var  = bnsq[t] * invN - mean * mean;
        float sc   = scale[t] * rsqrtf(var + 1e-5f);
        sA[t] = sc;
        bA[t] = bias[t] - mean * sc;
    }
    __syncthreads();
}

__launch_bounds__(256)
__global__ void k_bnapply_relu(const float4* __restrict__ gin,
                               const float* __restrict__ bnsum, const float* __restrict__ bnsq,
                               const float* __restrict__ scale, const float* __restrict__ bias,
                               float4* __restrict__ out)
{
    __shared__ float sA[128], bA[128];
    bn_coeffs(bnsum, bnsq, scale, bias, sA, bA);
    int idx = blockIdx.x * 256 + threadIdx.x;   // NN*128/4 threads
    int c4 = (idx & 31) * 4;
    float4 v = gin[idx];
    float4 r;
    r.x = fmaxf(fmaf(v.x, sA[c4 + 0], bA[c4 + 0]), 0.f);
    r.y = fmaxf(fmaf(v.y, sA[c4 + 1], bA[c4 + 1]), 0.f);
    r.z = fmaxf(fmaf(v.z, sA[c4 + 2], bA[c4 + 2]), 0.f);
    r.w = fmaxf(fmaf(v.w, sA[c4 + 3], bA[c4 + 3]), 0.f);
    out[idx] = r;
}

__launch_bounds__(256)
__global__ void k_bnapply_res_relu(const float4* __restrict__ gin,
                                   const float* __restrict__ bnsum, const float* __restrict__ bnsq,
                                   const float* __restrict__ scale, const float* __restrict__ bias,
                                   float4* __restrict__ hbuf)
{
    __shared__ float sA[128], bA[128];
    bn_coeffs(bnsum, bnsq, scale, bias, sA, bA);
    int idx = blockIdx.x * 256 + threadIdx.x;
    int c4 = (idx & 31) * 4;
    float4 v = gin[idx];
    float4 hv = hbuf[idx];
    float4 r;
    r.x = fmaxf(fmaf(v.x, sA[c4 + 0], bA[c4 + 0]) + hv.x, 0.f);
    r.y = fmaxf(fmaf(v.y, sA[c4 + 1], bA[c4 + 1]) + hv.y, 0.f);
    r.z = fmaxf(fmaf(v.z, sA[c4 + 2], bA[c4 + 2]) + hv.z, 0.f);
    r.w = fmaxf(fmaf(v.w, sA[c4 + 3], bA[c4 + 3]) + hv.w, 0.f);
    hbuf[idx] = r;
}

// ---------------- pooling + value head ----------------
// batch is sorted: segment-scan 128 consecutive rows/block, atomic only at boundaries.

__launch_bounds__(128)
__global__ void k_pool(const float* __restrict__ h, const int* __restrict__ batch,
                       float* __restrict__ pooled, float* __restrict__ cnt)
{
    int c = threadIdx.x;
    int r0 = blockIdx.x * 128;
    int cur = batch[r0];
    float acc = 0.f;
    float run = 0.f;
    for (int i = 0; i < 128; ++i) {
        int r = r0 + i;
        int b = batch[r];
        if (b != cur) {
            atomicAdd(&pooled[(size_t)cur * 128 + c], acc);
            if (c == 0) atomicAdd(&cnt[cur], run);
            acc = 0.f; run = 0.f; cur = b;
        }
        acc += h[(size_t)r * 128 + c];
        run += 1.f;
    }
    atomicAdd(&pooled[(size_t)cur * 128 + c], acc);
    if (c == 0) atomicAdd(&cnt[cur], run);
}

__launch_bounds__(64)
__global__ void k_value(const float* __restrict__ pooled, const float* __restrict__ cnt,
                        const float* __restrict__ Wv1, const float* __restrict__ bv1,
                        const float* __restrict__ Wv2, const float* __restrict__ bv2,
                        float* __restrict__ out)
{
    int gi = blockIdx.x;
    int l = threadIdx.x;
    float inv = 1.f / fmaxf(cnt[gi], 1.f);
    const float* pr = pooled + (size_t)gi * 128;
    float z = bv1[l];
    for (int k = 0; k < 128; k++) z = fmaf(pr[k] * inv, Wv1[k * 64 + l], z);
    z = fmaxf(z, 0.f);
#pragma unroll
    for (int j = 0; j < 3; j++) {
        float p = z * Wv2[l * 3 + j];
        p += __shfl_xor(p, 32); p += __shfl_xor(p, 16); p += __shfl_xor(p, 8);
        p += __shfl_xor(p, 4);  p += __shfl_xor(p, 2);  p += __shfl_xor(p, 1);
        if (l == 0) out[gi * 3 + j] = p + bv2[j];
    }
}

// ---------------- policy head ----------------
// policy[e] = relu(P1[src] + P2[dst] + ea@Wp1c + bp1) . Wp2 + bp2

__launch_bounds__(256)
__global__ void k_policy(const float* __restrict__ P1, const float* __restrict__ P2,
                         const float* __restrict__ eattr,
                         const int* __restrict__ src0, const int* __restrict__ dst0,
                         const float* __restrict__ Wp1c, const float* __restrict__ bp1,
                         const float* __restrict__ Wp2, const float* __restrict__ bp2,
                         float* __restrict__ out)
{
    int wave = (blockIdx.x * 256 + threadIdx.x) >> 6;   // 65536 waves
    int lane = threadIdx.x & 63;
    float w1c[12];
#pragma unroll
    for (int k = 0; k < 12; k++) w1c[k] = Wp1c[k * 64 + lane];
    float wp2 = Wp2[lane];
    float bb = bp1[lane];
    float b2 = bp2[0];
    for (int i = 0; i < 8; i++) {
        int e = wave * 8 + i;
        int sI = src0[e], dI = dst0[e];
        const float* ep = eattr + (size_t)e * 12;
        float4 e0 = *reinterpret_cast<const float4*>(ep);
        float4 e1 = *reinterpret_cast<const float4*>(ep + 4);
        float4 e2 = *reinterpret_cast<const float4*>(ep + 8);
        float z = P1[(size_t)sI * 64 + lane] + P2[(size_t)dI * 64 + lane] + bb;
        z += e0.x * w1c[0] + e0.y * w1c[1] + e0.z * w1c[2]  + e0.w * w1c[3]
           + e1.x * w1c[4] + e1.y * w1c[5] + e1.z * w1c[6]  + e1.w * w1c[7]
           + e2.x * w1c[8] + e2.y * w1c[9] + e2.z * w1c[10] + e2.w * w1c[11];
        z = fmaxf(z, 0.f);
        float p = z * wp2;
        p += __shfl_xor(p, 32); p += __shfl_xor(p, 16); p += __shfl_xor(p, 8);
        p += __shfl_xor(p, 4);  p += __shfl_xor(p, 2);  p += __shfl_xor(p, 1);
        if (lane == 0) out[3072 + e] = p + b2;
    }
}

// ---------------- host ----------------

extern "C" void kernel_launch(void* const* d_in, const int* in_sizes, int n_in,
                              void* d_out, int out_size, void* d_ws, size_t ws_size,
                              hipStream_t stream)
{
    const float* x     = (const float*)d_in[0];
    const float* eattr = (const float*)d_in[1];
    const int*   eidx  = (const int*)d_in[2];
    const int*   batch = (const int*)d_in[3];
    const float* Win   = (const float*)d_in[4];
    const float* bin   = (const float*)d_in[5];
    const float* Wl    = (const float*)d_in[6];
    const float* Wr    = (const float*)d_in[7];
    const float* We    = (const float*)d_in[8];
    const float* att   = (const float*)d_in[9];
    const float* bconv = (const float*)d_in[10];
    const float* bnsc  = (const float*)d_in[11];
    const float* bnbi  = (const float*)d_in[12];
    const float* Wv1   = (const float*)d_in[13];
    const float* bv1   = (const float*)d_in[14];
    const float* Wv2   = (const float*)d_in[15];
    const float* bv2   = (const float*)d_in[16];
    const float* Wp1   = (const float*)d_in[17];
    const float* bp1   = (const float*)d_in[18];
    const float* Wp2   = (const float*)d_in[19];
    const float* bp2   = (const float*)d_in[20];
    float* out = (float*)d_out;

    const int* src0 = eidx;
    const int* dst0 = eidx + EE;

    const size_t NH = (size_t)NN * 128;
    float* ws   = (float*)d_ws;
    float* h    = ws;               // N*128
    float* h1   = h + NH;
    float* g    = h1 + NH;
    float* xl   = g + NH;           // reused as P1 for policy head
    float* xr   = xl + NH;          // reused as P2
    float* mea  = xr + NH;          // N*12
    int* rowptr = (int*)(mea + (size_t)NN * 12);   // N+1
    int* csr_src= rowptr + (NN + 1);               // EPX
    int* csr_eid= csr_src + EPX;                   // EPX
    // --- zeroed region (one memset) ---
    int* deg    = csr_eid + EPX;    // N
    int* fill   = deg + NN;         // N
    float* bnstat = (float*)(fill + NN);     // 8 layers * 256 (sum|sq)
    float* pooled = bnstat + 8 * 256;        // G*128
    float* cnt    = pooled + (size_t)GG * 128;  // G
    size_t zero_elems = (size_t)NN + NN + 8 * 256 + (size_t)GG * 128 + GG;

    hipMemsetAsync(deg, 0, zero_elems * sizeof(float), stream);

    // CSR build
    k_deg<<<EE / 256, 256, 0, stream>>>(dst0, deg);
    k_scan<<<1, 1024, 0, stream>>>(deg, rowptr);
    k_scatter<<<EPX / 256, 256, 0, stream>>>(src0, dst0, rowptr, deg, fill, csr_src, csr_eid);
    k_mea<<<(NN * 16) / 256, 256, 0, stream>>>(rowptr, csr_eid, eattr, mea);

    // input layer
    k_input<<<NN / 16, 256, 0, stream>>>(x, Win, bin, h);

    // 8 GATv2 + BN layers
    for (int l = 0; l < 8; l++) {
        const float* hin = (l % 2 == 0) ? h : h1;
        float* bs = bnstat + l * 256;
        k_gemm_xlxr<<<dim3(NN / 64, 4), 256, 0, stream>>>(hin, Wl + (size_t)l * 16384,
                                                          Wr + (size_t)l * 16384, xl, xr);
        k_gat<<<NN / 4, 256, 0, stream>>>(xl, xr, eattr, mea, rowptr, csr_src, csr_eid,
                                          We + (size_t)l * 1536, att + (size_t)l * 128,
                                          bconv + (size_t)l * 128, g);
        k_bnstats<<<256, 256, 0, stream>>>(g, bs, bs + 128);
        if (l % 2 == 0)
            k_bnapply_relu<<<(NN * 128 / 4) / 256, 256, 0, stream>>>(
                (const float4*)g, bs, bs + 128, bnsc + (size_t)l * 128, bnbi + (size_t)l * 128,
                (float4*)h1);
        else
            k_bnapply_res_relu<<<(NN * 128 / 4) / 256, 256, 0, stream>>>(
                (const float4*)g, bs, bs + 128, bnsc + (size_t)l * 128, bnbi + (size_t)l * 128,
                (float4*)h);
    }

    // pooling + value head
    k_pool<<<NN / 128, 128, 0, stream>>>(h, batch, pooled, cnt);
    k_value<<<GG, 64, 0, stream>>>(pooled, cnt, Wv1, bv1, Wv2, bv2, out);

    // policy head: P1 = h @ Wp1[0:128], P2 = h @ Wp1[128:256]
    k_gemm64<<<NN / 64, 256, 0, stream>>>(h, Wp1, xl);
    k_gemm64<<<NN / 64, 256, 0, stream>>>(h, Wp1 + 128 * 64, xr);
    k_policy<<<NN / 4, 256, 0, stream>>>(xl, xr, eattr, src0, dst0,
                                         Wp1 + 256 * 64, bp1, Wp2, bp2, out);
}

// Round 3
// 2101.339 us; speedup vs baseline: 1.3283x; 1.1489x over previous
//
#include <hip/hip_runtime.h>

#define NN 65536
#define EE 524288
#define EPX 589824   // EE + NN
#define GG 1024

// ---------------- bf16 helpers ----------------

__device__ __forceinline__ unsigned short f2bf(float x) {
    unsigned int u = __float_as_uint(x);
    u += 0x7FFFu + ((u >> 16) & 1u);      // round-to-nearest-even
    return (unsigned short)(u >> 16);
}
__device__ __forceinline__ float bflo(unsigned int w) { return __uint_as_float(w << 16); }
__device__ __forceinline__ float bfhi(unsigned int w) { return __uint_as_float(w & 0xFFFF0000u); }

// ---------------- CSR build ----------------

__launch_bounds__(256)
__global__ void k_deg(const int* __restrict__ dst0, int* __restrict__ deg)
{
    int e = blockIdx.x * 256 + threadIdx.x;
    if (e >= EE) return;
    atomicAdd(&deg[dst0[e]], 1);
}

__launch_bounds__(1024)
__global__ void k_scan(const int* __restrict__ deg, int* __restrict__ rowptr)
{
    __shared__ int sums[1024];
    int t = threadIdx.x;
    int base = t * 64;
    int s = 0;
    for (int i = 0; i < 64; i++) s += deg[base + i] + 1;
    sums[t] = s;
    __syncthreads();
    for (int off = 1; off < 1024; off <<= 1) {
        int v = (t >= off) ? sums[t - off] : 0;
        __syncthreads();
        sums[t] += v;
        __syncthreads();
    }
    int off = sums[t] - s;   // exclusive prefix
    for (int i = 0; i < 64; i++) { rowptr[base + i] = off; off += deg[base + i] + 1; }
    if (t == 1023) rowptr[NN] = off;
}

// scatter edges into CSR order; also scatter edge attrs (bf16) into CSR order.
__launch_bounds__(256)
__global__ void k_scatter(const int* __restrict__ src0, const int* __restrict__ dst0,
                          const float* __restrict__ eattr,
                          const int* __restrict__ rowptr, const int* __restrict__ deg,
                          int* __restrict__ fill, int* __restrict__ csr_src,
                          unsigned short* __restrict__ eaCSR)
{
    int e = blockIdx.x * 256 + threadIdx.x;
    if (e >= EPX) return;
    if (e < EE) {
        int d = dst0[e];
        int pos = rowptr[d] + atomicAdd(&fill[d], 1);
        csr_src[pos] = src0[e];
        const float* ep = eattr + (size_t)e * 12;
        float4 a = *reinterpret_cast<const float4*>(ep);
        float4 b = *reinterpret_cast<const float4*>(ep + 4);
        float4 c = *reinterpret_cast<const float4*>(ep + 8);
        unsigned int w0 = (unsigned int)f2bf(a.x) | ((unsigned int)f2bf(a.y) << 16);
        unsigned int w1 = (unsigned int)f2bf(a.z) | ((unsigned int)f2bf(a.w) << 16);
        unsigned int w2 = (unsigned int)f2bf(b.x) | ((unsigned int)f2bf(b.y) << 16);
        unsigned int w3 = (unsigned int)f2bf(b.z) | ((unsigned int)f2bf(b.w) << 16);
        unsigned int w4 = (unsigned int)f2bf(c.x) | ((unsigned int)f2bf(c.y) << 16);
        unsigned int w5 = (unsigned int)f2bf(c.z) | ((unsigned int)f2bf(c.w) << 16);
        uint2* q = reinterpret_cast<uint2*>(eaCSR + (size_t)pos * 12);
        q[0] = make_uint2(w0, w1);
        q[1] = make_uint2(w2, w3);
        q[2] = make_uint2(w4, w5);
    } else {
        int n = e - EE;
        csr_src[rowptr[n] + deg[n]] = n;   // self-loop in the last slot
    }
}

// fill each node's self-loop attr slot with the mean of its real incoming edge attrs.
__launch_bounds__(256)
__global__ void k_selfattr(const int* __restrict__ rowptr, unsigned short* __restrict__ eaCSR)
{
    int tid = blockIdx.x * 256 + threadIdx.x;   // NN*16 threads
    int n = tid >> 4;
    int lk = tid & 15;
    if (lk >= 12) return;
    int beg = rowptr[n], endm1 = rowptr[n + 1] - 1;
    float s = 0.f;
    for (int p = beg; p < endm1; ++p)
        s += __uint_as_float(((unsigned int)eaCSR[(size_t)p * 12 + lk]) << 16);
    float dv = fmaxf((float)(endm1 - beg), 1.0f);
    eaCSR[(size_t)endm1 * 12 + lk] = f2bf(s / dv);
}

// ---------------- input layer: h = relu(x @ Win + bin) ----------------

__launch_bounds__(256)
__global__ void k_input(const float* __restrict__ x, const float* __restrict__ Win,
                        const float* __restrict__ bin, float* __restrict__ h)
{
    __shared__ float W[21 * 128];
    int t = threadIdx.x;
    for (int i = t; i < 21 * 128; i += 256) W[i] = Win[i];
    __syncthreads();
    int c = t & 127, sub = t >> 7;
    int n0 = blockIdx.x * 16;
    float bc = bin[c];
    for (int i = 0; i < 8; i++) {
        int n = n0 + sub + i * 2;
        const float* xp = x + (size_t)n * 21;
        float acc = bc;
#pragma unroll
        for (int k = 0; k < 21; k++) acc = fmaf(xp[k], W[k * 128 + c], acc);
        h[(size_t)n * 128 + c] = fmaxf(acc, 0.f);
    }
}

// ---------------- GEMM bodies ----------------

__device__ __forceinline__ void gemm_core(const float* __restrict__ A, const float* __restrict__ B,
                                          int ldb, int rowBase, int colBase,
                                          float acc[4][4], float* As, float* Bs)
{
    int t = threadIdx.x;
#pragma unroll
    for (int i = 0; i < 8; i++) {
        int f = i * 256 + t;
        int r = f >> 5, c4 = f & 31;
        float4 v = *reinterpret_cast<const float4*>(A + (size_t)(rowBase + r) * 128 + c4 * 4);
        *reinterpret_cast<float4*>(&As[r * 132 + c4 * 4]) = v;
    }
#pragma unroll
    for (int i = 0; i < 8; i++) {
        int f = i * 256 + t;
        int r = f >> 4, c4 = f & 15;
        float4 v = *reinterpret_cast<const float4*>(B + (size_t)r * ldb + colBase + c4 * 4);
        *reinterpret_cast<float4*>(&Bs[r * 68 + c4 * 4]) = v;
    }
    __syncthreads();
    int tx = t & 15, ty = t >> 4;
#pragma unroll
    for (int i = 0; i < 4; i++)
#pragma unroll
        for (int j = 0; j < 4; j++) acc[i][j] = 0.f;

    for (int k = 0; k < 128; k += 4) {
        float a[4][4], b[4][4];
#pragma unroll
        for (int i = 0; i < 4; i++)
            *reinterpret_cast<float4*>(&a[i][0]) =
                *reinterpret_cast<const float4*>(&As[(ty * 4 + i) * 132 + k]);
#pragma unroll
        for (int kk = 0; kk < 4; kk++)
            *reinterpret_cast<float4*>(&b[kk][0]) =
                *reinterpret_cast<const float4*>(&Bs[(k + kk) * 68 + tx * 4]);
#pragma unroll
        for (int kk = 0; kk < 4; kk++)
#pragma unroll
            for (int i = 0; i < 4; i++)
#pragma unroll
                for (int j = 0; j < 4; j++)
                    acc[i][j] = fmaf(a[i][kk], b[kk][j], acc[i][j]);
    }
}

// xl and xr in one dispatch, bf16 output: grid.y 0..3 (y<2 -> xl cols 0/64; y>=2 -> xr)
__launch_bounds__(256)
__global__ void k_gemm_xlxr(const float* __restrict__ A, const float* __restrict__ Bl,
                            const float* __restrict__ Br, unsigned short* __restrict__ Cl,
                            unsigned short* __restrict__ Cr)
{
    __shared__ float As[64 * 132];
    __shared__ float Bs[128 * 68];
    int yb = blockIdx.y;
    const float* B = (yb < 2) ? Bl : Br;
    unsigned short* C = (yb < 2) ? Cl : Cr;
    int rowBase = blockIdx.x * 64, colBase = (yb & 1) * 64;
    float acc[4][4];
    gemm_core(A, B, 128, rowBase, colBase, acc, As, Bs);
    int tx = threadIdx.x & 15, ty = threadIdx.x >> 4;
#pragma unroll
    for (int i = 0; i < 4; i++) {
        unsigned int w0 = (unsigned int)f2bf(acc[i][0]) | ((unsigned int)f2bf(acc[i][1]) << 16);
        unsigned int w1 = (unsigned int)f2bf(acc[i][2]) | ((unsigned int)f2bf(acc[i][3]) << 16);
        *reinterpret_cast<uint2*>(C + (size_t)(rowBase + ty * 4 + i) * 128 + colBase + tx * 4) =
            make_uint2(w0, w1);
    }
}

// fp32-out GEMM for the policy projections (N=64)
__launch_bounds__(256)
__global__ void k_gemm64(const float* __restrict__ A, const float* __restrict__ B,
                         float* __restrict__ C)
{
    __shared__ float As[64 * 132];
    __shared__ float Bs[128 * 68];
    float acc[4][4];
    int rowBase = blockIdx.x * 64;
    gemm_core(A, B, 64, rowBase, 0, acc, As, Bs);
    int tx = threadIdx.x & 15, ty = threadIdx.x >> 4;
#pragma unroll
    for (int i = 0; i < 4; i++) {
        float4 v; v.x = acc[i][0]; v.y = acc[i][1]; v.z = acc[i][2]; v.w = acc[i][3];
        *reinterpret_cast<float4*>(C + (size_t)(rowBase + ty * 4 + i) * 64 + tx * 4) = v;
    }
}

// ---------------- GATv2 edge aggregation: one wave per dst node ----------------
// lane l owns features f0=2l, f0+1 (head = l>>4); online softmax per head; 2-edge unroll.
// xl/xr bf16; edge attrs bf16 in CSR order.

__launch_bounds__(256)
__global__ void k_gat(const unsigned short* __restrict__ xlb, const unsigned short* __restrict__ xrb,
                      const unsigned short* __restrict__ eaCSR,
                      const int* __restrict__ rowptr, const int* __restrict__ csr_src,
                      const float* __restrict__ We, const float* __restrict__ att,
                      const float* __restrict__ bconv, float* __restrict__ g)
{
    int wave = threadIdx.x >> 6, lane = threadIdx.x & 63;
    int n = blockIdx.x * 4 + wave;
    int f0 = lane * 2;

    float wex[12], wey[12];
#pragma unroll
    for (int k = 0; k < 12; k++) {
        float2 w = *reinterpret_cast<const float2*>(We + k * 128 + f0);
        wex[k] = w.x; wey[k] = w.y;
    }
    float2 av = *reinterpret_cast<const float2*>(att + f0);
    unsigned int xrw = *reinterpret_cast<const unsigned int*>(xrb + (size_t)n * 128 + f0);
    float xr0 = bflo(xrw), xr1 = bfhi(xrw);

    float m = -INFINITY, s = 0.f, a0 = 0.f, a1 = 0.f;
    int beg = rowptr[n], end = rowptr[n + 1];
    int idx = beg;
    for (; idx + 2 <= end; idx += 2) {
        int s0 = csr_src[idx], s1 = csr_src[idx + 1];
        const uint2* q0 = reinterpret_cast<const uint2*>(eaCSR + (size_t)idx * 12);
        uint2 qa = q0[0], qb = q0[1], qc = q0[2];
        uint2 ra = q0[3], rb = q0[4], rc = q0[5];   // next edge's 12 bf16 (contiguous)
        unsigned int xw0 = *reinterpret_cast<const unsigned int*>(xlb + (size_t)s0 * 128 + f0);
        unsigned int xw1 = *reinterpret_cast<const unsigned int*>(xlb + (size_t)s1 * 128 + f0);

        float e0[12], e1[12];
        e0[0] = bflo(qa.x); e0[1] = bfhi(qa.x); e0[2]  = bflo(qa.y); e0[3]  = bfhi(qa.y);
        e0[4] = bflo(qb.x); e0[5] = bfhi(qb.x); e0[6]  = bflo(qb.y); e0[7]  = bfhi(qb.y);
        e0[8] = bflo(qc.x); e0[9] = bfhi(qc.x); e0[10] = bflo(qc.y); e0[11] = bfhi(qc.y);
        e1[0] = bflo(ra.x); e1[1] = bfhi(ra.x); e1[2]  = bflo(ra.y); e1[3]  = bfhi(ra.y);
        e1[4] = bflo(rb.x); e1[5] = bfhi(rb.x); e1[6]  = bflo(rb.y); e1[7]  = bfhi(rb.y);
        e1[8] = bflo(rc.x); e1[9] = bfhi(rc.x); e1[10] = bflo(rc.y); e1[11] = bfhi(rc.y);

        float ex0 = 0.f, ey0 = 0.f, ex1 = 0.f, ey1 = 0.f;
#pragma unroll
        for (int k = 0; k < 12; k++) {
            ex0 = fmaf(e0[k], wex[k], ex0); ey0 = fmaf(e0[k], wey[k], ey0);
            ex1 = fmaf(e1[k], wex[k], ex1); ey1 = fmaf(e1[k], wey[k], ey1);
        }
        float xa0 = bflo(xw0), xa1 = bfhi(xw0);
        float xb0 = bflo(xw1), xb1 = bfhi(xw1);

        float m00 = xa0 + xr0 + ex0, m01 = xa1 + xr1 + ey0;
        float m10 = xb0 + xr0 + ex1, m11 = xb1 + xr1 + ey1;
        float v00 = (m00 > 0.f) ? m00 : 0.2f * m00;
        float v01 = (m01 > 0.f) ? m01 : 0.2f * m01;
        float v10 = (m10 > 0.f) ? m10 : 0.2f * m10;
        float v11 = (m11 > 0.f) ? m11 : 0.2f * m11;
        float t0 = v00 * av.x + v01 * av.y;
        float t1 = v10 * av.x + v11 * av.y;
        t0 += __shfl_xor(t0, 1);  t1 += __shfl_xor(t1, 1);
        t0 += __shfl_xor(t0, 2);  t1 += __shfl_xor(t1, 2);
        t0 += __shfl_xor(t0, 4);  t1 += __shfl_xor(t1, 4);
        t0 += __shfl_xor(t0, 8);  t1 += __shfl_xor(t1, 8);

        float nm = fmaxf(m, fmaxf(t0, t1));
        float so = __expf(m - nm);
        float w0 = __expf(t0 - nm);
        float w1 = __expf(t1 - nm);
        s  = s * so + w0 + w1;
        a0 = a0 * so + w0 * xa0 + w1 * xb0;
        a1 = a1 * so + w0 * xa1 + w1 * xb1;
        m = nm;
    }
    if (idx < end) {
        int s0 = csr_src[idx];
        const uint2* q0 = reinterpret_cast<const uint2*>(eaCSR + (size_t)idx * 12);
        uint2 qa = q0[0], qb = q0[1], qc = q0[2];
        unsigned int xw0 = *reinterpret_cast<const unsigned int*>(xlb + (size_t)s0 * 128 + f0);
        float e0[12];
        e0[0] = bflo(qa.x); e0[1] = bfhi(qa.x); e0[2]  = bflo(qa.y); e0[3]  = bfhi(qa.y);
        e0[4] = bflo(qb.x); e0[5] = bfhi(qb.x); e0[6]  = bflo(qb.y); e0[7]  = bfhi(qb.y);
        e0[8] = bflo(qc.x); e0[9] = bfhi(qc.x); e0[10] = bflo(qc.y); e0[11] = bfhi(qc.y);
        float ex0 = 0.f, ey0 = 0.f;
#pragma unroll
        for (int k = 0; k < 12; k++) {
            ex0 = fmaf(e0[k], wex[k], ex0); ey0 = fmaf(e0[k], wey[k], ey0);
        }
        float xa0 = bflo(xw0), xa1 = bfhi(xw0);
        float m0 = xa0 + xr0 + ex0;
        float m1 = xa1 + xr1 + ey0;
        float v0 = (m0 > 0.f) ? m0 : 0.2f * m0;
        float v1 = (m1 > 0.f) ? m1 : 0.2f * m1;
        float tt = v0 * av.x + v1 * av.y;
        tt += __shfl_xor(tt, 1);
        tt += __shfl_xor(tt, 2);
        tt += __shfl_xor(tt, 4);
        tt += __shfl_xor(tt, 8);
        float nm = fmaxf(m, tt);
        float so = __expf(m - nm);
        float w  = __expf(tt - nm);
        s  = s * so + w;
        a0 = a0 * so + w * xa0;
        a1 = a1 * so + w * xa1;
        m = nm;
    }
    float inv = 1.f / s;   // s > 0 guaranteed by the self-loop
    float2 bc = *reinterpret_cast<const float2*>(bconv + f0);
    float2 r; r.x = a0 * inv + bc.x; r.y = a1 * inv + bc.y;
    *reinterpret_cast<float2*>(g + (size_t)n * 128 + f0) = r;
}

// ---------------- BatchNorm ----------------

__launch_bounds__(256)
__global__ void k_bnstats(const float* __restrict__ X, float* __restrict__ sum, float* __restrict__ sq)
{
    int col = threadIdx.x & 127;
    int half = threadIdx.x >> 7;
    int rbase = blockIdx.x * 256 + half;
    float s = 0.f, q = 0.f;
    for (int i = 0; i < 128; i++) {
        float v = X[(size_t)(rbase + i * 2) * 128 + col];
        s += v; q += v * v;
    }
    __shared__ float ls[256], lq[256];
    ls[threadIdx.x] = s; lq[threadIdx.x] = q;
    __syncthreads();
    if (half == 0) {
        s += ls[threadIdx.x + 128];
        q += lq[threadIdx.x + 128];
        atomicAdd(&sum[col], s);
        atomicAdd(&sq[col], q);
    }
}

__device__ __forceinline__ void bn_coeffs(const float* __restrict__ bnsum, const float* __restrict__ bnsq,
                                          const float* __restrict__ scale, const float* __restrict__ bias,
                                          float* sA, float* bA)
{
    int t = threadIdx.x;
    if (t < 128) {
        const float invN = 1.0f / (float)NN;
        float mean = bnsum[t] * invN;
        float var  = bnsq[t] * invN - mean * mean;
        float sc   = scale[t] * rsqrtf(var + 1e-5f);
        sA[t] = sc;
        bA[t] = bias[t] - mean * sc;
    }
    __syncthreads();
}

__launch_bounds__(256)
__global__ void k_bnapply_relu(const float4* __restrict__ gin,
                               const float* __restrict__ bnsum, const float* __restrict__ bnsq,
                               const float* __restrict__ scale, const float* __restrict__ bias,
                               float4* __restrict__ out)
{
    __shared__ float sA[128], bA[128];
    bn_coeffs(bnsum, bnsq, scale, bias, sA, bA);
    int idx = blockIdx.x * 256 + threadIdx.x;   // NN*128/4 threads
    int c4 = (idx & 31) * 4;
    float4 v = gin[idx];
    float4 r;
    r.x = fmaxf(fmaf(v.x, sA[c4 + 0], bA[c4 + 0]), 0.f);
    r.y = fmaxf(fmaf(v.y, sA[c4 + 1], bA[c4 + 1]), 0.f);
    r.z = fmaxf(fmaf(v.z, sA[c4 + 2], bA[c4 + 2]), 0.f);
    r.w = fmaxf(fmaf(v.w, sA[c4 + 3], bA[c4 + 3]), 0.f);
    out[idx] = r;
}

__launch_bounds__(256)
__global__ void k_bnapply_res_relu(const float4* __restrict__ gin,
                                   const float* __restrict__ bnsum, const float* __restrict__ bnsq,
                                   const float* __restrict__ scale, const float* __restrict__ bias,
                                   float4* __restrict__ hbuf)
{
    __shared__ float sA[128], bA[128];
    bn_coeffs(bnsum, bnsq, scale, bias, sA, bA);
    int idx = blockIdx.x * 256 + threadIdx.x;
    int c4 = (idx & 31) * 4;
    float4 v = gin[idx];
    float4 hv = hbuf[idx];
    float4 r;
    r.x = fmaxf(fmaf(v.x, sA[c4 + 0], bA[c4 + 0]) + hv.x, 0.f);
    r.y = fmaxf(fmaf(v.y, sA[c4 + 1], bA[c4 + 1]) + hv.y, 0.f);
    r.z = fmaxf(fmaf(v.z, sA[c4 + 2], bA[c4 + 2]) + hv.z, 0.f);
    r.w = fmaxf(fmaf(v.w, sA[c4 + 3], bA[c4 + 3]) + hv.w, 0.f);
    hbuf[idx] = r;
}

// ---------------- pooling + value head ----------------

__launch_bounds__(128)
__global__ void k_pool(const float* __restrict__ h, const int* __restrict__ batch,
                       float* __restrict__ pooled, float* __restrict__ cnt)
{
    int c = threadIdx.x;
    int r0 = blockIdx.x * 128;
    int cur = batch[r0];
    float acc = 0.f;
    float run = 0.f;
    for (int i = 0; i < 128; ++i) {
        int r = r0 + i;
        int b = batch[r];
        if (b != cur) {
            atomicAdd(&pooled[(size_t)cur * 128 + c], acc);
            if (c == 0) atomicAdd(&cnt[cur], run);
            acc = 0.f; run = 0.f; cur = b;
        }
        acc += h[(size_t)r * 128 + c];
        run += 1.f;
    }
    atomicAdd(&pooled[(size_t)cur * 128 + c], acc);
    if (c == 0) atomicAdd(&cnt[cur], run);
}

__launch_bounds__(64)
__global__ void k_value(const float* __restrict__ pooled, const float* __restrict__ cnt,
                        const float* __restrict__ Wv1, const float* __restrict__ bv1,
                        const float* __restrict__ Wv2, const float* __restrict__ bv2,
                        float* __restrict__ out)
{
    int gi = blockIdx.x;
    int l = threadIdx.x;
    float inv = 1.f / fmaxf(cnt[gi], 1.f);
    const float* pr = pooled + (size_t)gi * 128;
    float z = bv1[l];
    for (int k = 0; k < 128; k++) z = fmaf(pr[k] * inv, Wv1[k * 64 + l], z);
    z = fmaxf(z, 0.f);
#pragma unroll
    for (int j = 0; j < 3; j++) {
        float p = z * Wv2[l * 3 + j];
        p += __shfl_xor(p, 32); p += __shfl_xor(p, 16); p += __shfl_xor(p, 8);
        p += __shfl_xor(p, 4);  p += __shfl_xor(p, 2);  p += __shfl_xor(p, 1);
        if (l == 0) out[gi * 3 + j] = p + bv2[j];
    }
}

// ---------------- policy head ----------------
// policy[e] = relu(P1[src] + P2[dst] + ea@Wp1c + bp1) . Wp2 + bp2

__launch_bounds__(256)
__global__ void k_policy(const float* __restrict__ P1, const float* __restrict__ P2,
                         const float* __restrict__ eattr,
                         const int* __restrict__ src0, const int* __restrict__ dst0,
                         const float* __restrict__ Wp1c, const float* __restrict__ bp1,
                         const float* __restrict__ Wp2, const float* __restrict__ bp2,
                         float* __restrict__ out)
{
    int wave = (blockIdx.x * 256 + threadIdx.x) >> 6;   // 65536 waves
    int lane = threadIdx.x & 63;
    float w1c[12];
#pragma unroll
    for (int k = 0; k < 12; k++) w1c[k] = Wp1c[k * 64 + lane];
    float wp2 = Wp2[lane];
    float bb = bp1[lane];
    float b2 = bp2[0];
    for (int i = 0; i < 8; i++) {
        int e = wave * 8 + i;
        int sI = src0[e], dI = dst0[e];
        const float* ep = eattr + (size_t)e * 12;
        float4 e0 = *reinterpret_cast<const float4*>(ep);
        float4 e1 = *reinterpret_cast<const float4*>(ep + 4);
        float4 e2 = *reinterpret_cast<const float4*>(ep + 8);
        float z = P1[(size_t)sI * 64 + lane] + P2[(size_t)dI * 64 + lane] + bb;
        z += e0.x * w1c[0] + e0.y * w1c[1] + e0.z * w1c[2]  + e0.w * w1c[3]
           + e1.x * w1c[4] + e1.y * w1c[5] + e1.z * w1c[6]  + e1.w * w1c[7]
           + e2.x * w1c[8] + e2.y * w1c[9] + e2.z * w1c[10] + e2.w * w1c[11];
        z = fmaxf(z, 0.f);
        float p = z * wp2;
        p += __shfl_xor(p, 32); p += __shfl_xor(p, 16); p += __shfl_xor(p, 8);
        p += __shfl_xor(p, 4);  p += __shfl_xor(p, 2);  p += __shfl_xor(p, 1);
        if (lane == 0) out[3072 + e] = p + b2;
    }
}

// ---------------- host ----------------

extern "C" void kernel_launch(void* const* d_in, const int* in_sizes, int n_in,
                              void* d_out, int out_size, void* d_ws, size_t ws_size,
                              hipStream_t stream)
{
    const float* x     = (const float*)d_in[0];
    const float* eattr = (const float*)d_in[1];
    const int*   eidx  = (const int*)d_in[2];
    const int*   batch = (const int*)d_in[3];
    const float* Win   = (const float*)d_in[4];
    const float* bin   = (const float*)d_in[5];
    const float* Wl    = (const float*)d_in[6];
    const float* Wr    = (const float*)d_in[7];
    const float* We    = (const float*)d_in[8];
    const float* att   = (const float*)d_in[9];
    const float* bconv = (const float*)d_in[10];
    const float* bnsc  = (const float*)d_in[11];
    const float* bnbi  = (const float*)d_in[12];
    const float* Wv1   = (const float*)d_in[13];
    const float* bv1   = (const float*)d_in[14];
    const float* Wv2   = (const float*)d_in[15];
    const float* bv2   = (const float*)d_in[16];
    const float* Wp1   = (const float*)d_in[17];
    const float* bp1   = (const float*)d_in[18];
    const float* Wp2   = (const float*)d_in[19];
    const float* bp2   = (const float*)d_in[20];
    float* out = (float*)d_out;

    const int* src0 = eidx;
    const int* dst0 = eidx + EE;

    const size_t NH = (size_t)NN * 128;
    float* ws = (float*)d_ws;
    float* h  = ws;                    // N*128 fp32
    float* h1 = h + NH;                // N*128 fp32
    float* g  = h1 + NH;               // N*128 fp32 (reused: P1 = g, P2 = g + N*64)
    unsigned short* xlb = (unsigned short*)(g + NH);        // N*128 bf16
    unsigned short* xrb = xlb + NH;                          // N*128 bf16
    unsigned short* eaCSR = xrb + NH;                        // EPX*12 bf16
    int* rowptr = (int*)(eaCSR + (size_t)EPX * 12);          // N+1
    int* csr_src = rowptr + (NN + 1);                        // EPX
    // --- zeroed region (one memset) ---
    int* deg  = csr_src + EPX;         // N
    int* fill = deg + NN;              // N
    float* bnstat = (float*)(fill + NN);        // 8 layers * 256 (sum|sq)
    float* pooled = bnstat + 8 * 256;           // G*128
    float* cnt    = pooled + (size_t)GG * 128;  // G
    size_t zero_elems = (size_t)NN + NN + 8 * 256 + (size_t)GG * 128 + GG;

    hipMemsetAsync(deg, 0, zero_elems * sizeof(float), stream);

    // CSR build
    k_deg<<<EE / 256, 256, 0, stream>>>(dst0, deg);
    k_scan<<<1, 1024, 0, stream>>>(deg, rowptr);
    k_scatter<<<EPX / 256, 256, 0, stream>>>(src0, dst0, eattr, rowptr, deg, fill, csr_src, eaCSR);
    k_selfattr<<<(NN * 16) / 256, 256, 0, stream>>>(rowptr, eaCSR);

    // input layer
    k_input<<<NN / 16, 256, 0, stream>>>(x, Win, bin, h);

    // 8 GATv2 + BN layers
    for (int l = 0; l < 8; l++) {
        const float* hin = (l % 2 == 0) ? h : h1;
        float* bs = bnstat + l * 256;
        k_gemm_xlxr<<<dim3(NN / 64, 4), 256, 0, stream>>>(hin, Wl + (size_t)l * 16384,
                                                          Wr + (size_t)l * 16384, xlb, xrb);
        k_gat<<<NN / 4, 256, 0, stream>>>(xlb, xrb, eaCSR, rowptr, csr_src,
                                          We + (size_t)l * 1536, att + (size_t)l * 128,
                                          bconv + (size_t)l * 128, g);
        k_bnstats<<<256, 256, 0, stream>>>(g, bs, bs + 128);
        if (l % 2 == 0)
            k_bnapply_relu<<<(NN * 128 / 4) / 256, 256, 0, stream>>>(
                (const float4*)g, bs, bs + 128, bnsc + (size_t)l * 128, bnbi + (size_t)l * 128,
                (float4*)h1);
        else
            k_bnapply_res_relu<<<(NN * 128 / 4) / 256, 256, 0, stream>>>(
                (const float4*)g, bs, bs + 128, bnsc + (size_t)l * 128, bnbi + (size_t)l * 128,
                (float4*)h);
    }

    // pooling + value head
    k_pool<<<NN / 128, 128, 0, stream>>>(h, batch, pooled, cnt);
    k_value<<<GG, 64, 0, stream>>>(pooled, cnt, Wv1, bv1, Wv2, bv2, out);

    // policy head: P1 = h @ Wp1[0:128], P2 = h @ Wp1[128:256]
    float* P1 = g;
    float* P2 = g + (size_t)NN * 64;
    k_gemm64<<<NN / 64, 256, 0, stream>>>(h, Wp1, P1);
    k_gemm64<<<NN / 64, 256, 0, stream>>>(h, Wp1 + 128 * 64, P2);
    k_policy<<<NN / 4, 256, 0, stream>>>(P1, P2, eattr, src0, dst0,
                                         Wp1 + 256 * 64, bp1, Wp2, bp2, out);
}

// Round 4
// 1423.952 us; speedup vs baseline: 1.9602x; 1.4757x over previous
//
#include <hip/hip_runtime.h>

#define NN 65536
#define EE 524288
#define EPX 589824   // EE + NN
#define GG 1024

typedef __attribute__((ext_vector_type(8))) short bf16x8;
typedef __attribute__((ext_vector_type(4))) float f32x4;

// ---------------- bf16 helpers ----------------

__device__ __forceinline__ unsigned short f2bf(float x) {
    unsigned int u = __float_as_uint(x);
    u += 0x7FFFu + ((u >> 16) & 1u);      // round-to-nearest-even
    return (unsigned short)(u >> 16);
}
__device__ __forceinline__ float bflo(unsigned int w) { return __uint_as_float(w << 16); }
__device__ __forceinline__ float bfhi(unsigned int w) { return __uint_as_float(w & 0xFFFF0000u); }

// ---------------- CSR build ----------------

__launch_bounds__(256)
__global__ void k_deg(const int* __restrict__ dst0, int* __restrict__ deg)
{
    int e = blockIdx.x * 256 + threadIdx.x;
    if (e >= EE) return;
    atomicAdd(&deg[dst0[e]], 1);
}

__launch_bounds__(1024)
__global__ void k_scan(const int* __restrict__ deg, int* __restrict__ rowptr)
{
    __shared__ int sums[1024];
    int t = threadIdx.x;
    int base = t * 64;
    int s = 0;
    for (int i = 0; i < 64; i++) s += deg[base + i] + 1;
    sums[t] = s;
    __syncthreads();
    for (int off = 1; off < 1024; off <<= 1) {
        int v = (t >= off) ? sums[t - off] : 0;
        __syncthreads();
        sums[t] += v;
        __syncthreads();
    }
    int off = sums[t] - s;   // exclusive prefix
    for (int i = 0; i < 64; i++) { rowptr[base + i] = off; off += deg[base + i] + 1; }
    if (t == 1023) rowptr[NN] = off;
}

// scatter edges into CSR order; also scatter edge attrs (bf16) into CSR order.
__launch_bounds__(256)
__global__ void k_scatter(const int* __restrict__ src0, const int* __restrict__ dst0,
                          const float* __restrict__ eattr,
                          const int* __restrict__ rowptr, const int* __restrict__ deg,
                          int* __restrict__ fill, int* __restrict__ csr_src,
                          unsigned short* __restrict__ eaCSR)
{
    int e = blockIdx.x * 256 + threadIdx.x;
    if (e >= EPX) return;
    if (e < EE) {
        int d = dst0[e];
        int pos = rowptr[d] + atomicAdd(&fill[d], 1);
        csr_src[pos] = src0[e];
        const float* ep = eattr + (size_t)e * 12;
        float4 a = *reinterpret_cast<const float4*>(ep);
        float4 b = *reinterpret_cast<const float4*>(ep + 4);
        float4 c = *reinterpret_cast<const float4*>(ep + 8);
        unsigned int w0 = (unsigned int)f2bf(a.x) | ((unsigned int)f2bf(a.y) << 16);
        unsigned int w1 = (unsigned int)f2bf(a.z) | ((unsigned int)f2bf(a.w) << 16);
        unsigned int w2 = (unsigned int)f2bf(b.x) | ((unsigned int)f2bf(b.y) << 16);
        unsigned int w3 = (unsigned int)f2bf(b.z) | ((unsigned int)f2bf(b.w) << 16);
        unsigned int w4 = (unsigned int)f2bf(c.x) | ((unsigned int)f2bf(c.y) << 16);
        unsigned int w5 = (unsigned int)f2bf(c.z) | ((unsigned int)f2bf(c.w) << 16);
        uint2* q = reinterpret_cast<uint2*>(eaCSR + (size_t)pos * 12);
        q[0] = make_uint2(w0, w1);
        q[1] = make_uint2(w2, w3);
        q[2] = make_uint2(w4, w5);
    } else {
        int n = e - EE;
        csr_src[rowptr[n] + deg[n]] = n;   // self-loop in the last slot
    }
}

// fill each node's self-loop attr slot with the mean of its real incoming edge attrs.
__launch_bounds__(256)
__global__ void k_selfattr(const int* __restrict__ rowptr, unsigned short* __restrict__ eaCSR)
{
    int tid = blockIdx.x * 256 + threadIdx.x;   // NN*16 threads
    int n = tid >> 4;
    int lk = tid & 15;
    if (lk >= 12) return;
    int beg = rowptr[n], endm1 = rowptr[n + 1] - 1;
    float s = 0.f;
    for (int p = beg; p < endm1; ++p)
        s += __uint_as_float(((unsigned int)eaCSR[(size_t)p * 12 + lk]) << 16);
    float dv = fmaxf((float)(endm1 - beg), 1.0f);
    eaCSR[(size_t)endm1 * 12 + lk] = f2bf(s / dv);
}

// ---------------- MFMA weight prep: swizzle W into 16x16x32 B-fragment order ----------------
// GAT: wg[l][kt(4)][ct(16)][lane(64)][j(8)], B = [Wl | Wr] (128 x 256), elem = W[k][col],
//      k = kt*32 + (lane>>4)*8 + j, col = ct*16 + (lane&15).
// Policy: wp[kt(4)][ct(8)][lane][j], B 128x128 = [Wp1[0:128] | Wp1[128:256]].

__launch_bounds__(256)
__global__ void k_wprep(const float* __restrict__ Wl, const float* __restrict__ Wr,
                        const float* __restrict__ Wp1,
                        unsigned short* __restrict__ wg, unsigned short* __restrict__ wp)
{
    int tid = blockIdx.x * 256 + threadIdx.x;   // 34816 threads
    if (tid < 32768) {
        int l = tid >> 12;
        int r = tid & 4095;
        int kt = r >> 10, ct = (r >> 6) & 15, lane = r & 63;
        int kb = kt * 32 + (lane >> 4) * 8;
        int col = ct * 16 + (lane & 15);
        const float* W = (col < 128) ? (Wl + (size_t)l * 16384 + col)
                                     : (Wr + (size_t)l * 16384 + (col - 128));
        unsigned short* o = wg + (size_t)tid * 8;
#pragma unroll
        for (int j = 0; j < 8; j++) o[j] = f2bf(W[(size_t)(kb + j) * 128]);
    } else if (tid < 34816) {
        int r = tid - 32768;
        int kt = r >> 9, ct = (r >> 6) & 7, lane = r & 63;
        int kb = kt * 32 + (lane >> 4) * 8;
        int col = ct * 16 + (lane & 15);
        const float* W = (col < 64) ? (Wp1 + col) : (Wp1 + 128 * 64 + (col - 64));
        unsigned short* o = wp + (size_t)r * 8;
#pragma unroll
        for (int j = 0; j < 8; j++) o[j] = f2bf(W[(size_t)(kb + j) * 64]);
    }
}

// ---------------- input layer: h = relu(x @ Win + bin) ----------------

__launch_bounds__(256)
__global__ void k_input(const float* __restrict__ x, const float* __restrict__ Win,
                        const float* __restrict__ bin, float* __restrict__ h)
{
    __shared__ float W[21 * 128];
    int t = threadIdx.x;
    for (int i = t; i < 21 * 128; i += 256) W[i] = Win[i];
    __syncthreads();
    int c = t & 127, sub = t >> 7;
    int n0 = blockIdx.x * 16;
    float bc = bin[c];
    for (int i = 0; i < 8; i++) {
        int n = n0 + sub + i * 2;
        const float* xp = x + (size_t)n * 21;
        float acc = bc;
#pragma unroll
        for (int k = 0; k < 21; k++) acc = fmaf(xp[k], W[k * 128 + c], acc);
        h[(size_t)n * 128 + c] = fmaxf(acc, 0.f);
    }
}

// ---------------- MFMA GEMMs (no LDS; A fp32 -> bf16 in-register; B pre-swizzled) ----------------

__device__ __forceinline__ void load_afrag(const float* __restrict__ A, int arow, int kb,
                                           bf16x8 af[4])
{
#pragma unroll
    for (int kt = 0; kt < 4; kt++) {
        const float* ap = A + (size_t)arow * 128 + kt * 32 + kb;
        float4 lo = *reinterpret_cast<const float4*>(ap);
        float4 hi = *reinterpret_cast<const float4*>(ap + 4);
        bf16x8 v;
        v[0] = (short)f2bf(lo.x); v[1] = (short)f2bf(lo.y);
        v[2] = (short)f2bf(lo.z); v[3] = (short)f2bf(lo.w);
        v[4] = (short)f2bf(hi.x); v[5] = (short)f2bf(hi.y);
        v[6] = (short)f2bf(hi.z); v[7] = (short)f2bf(hi.w);
        af[kt] = v;
    }
}

// xl|xr: C (bf16) = A[N,128] @ B[128,256]; cols<128 -> Cl, else Cr
__launch_bounds__(256)
__global__ void k_gemm_gat(const float* __restrict__ A, const unsigned short* __restrict__ Bf,
                           unsigned short* __restrict__ Cl, unsigned short* __restrict__ Cr)
{
    int wave = threadIdx.x >> 6, lane = threadIdx.x & 63;
    int row0 = blockIdx.x * 64 + wave * 16;
    int arow = row0 + (lane & 15);
    int kb = (lane >> 4) * 8;
    bf16x8 af[4];
    load_afrag(A, arow, kb, af);
    int crow = row0 + (lane >> 4) * 4;
    int c0 = lane & 15;
#pragma unroll
    for (int ct = 0; ct < 16; ct++) {
        f32x4 acc = {0.f, 0.f, 0.f, 0.f};
#pragma unroll
        for (int kt = 0; kt < 4; kt++) {
            bf16x8 bf = *reinterpret_cast<const bf16x8*>(Bf + ((size_t)(kt * 16 + ct) * 64 + lane) * 8);
            acc = __builtin_amdgcn_mfma_f32_16x16x32_bf16(af[kt], bf, acc, 0, 0, 0);
        }
        int col = ct * 16 + c0;
        unsigned short* C = (col < 128) ? Cl : Cr;
        int cc = col & 127;
#pragma unroll
        for (int r = 0; r < 4; r++)
            C[(size_t)(crow + r) * 128 + cc] = f2bf(acc[r]);
    }
}

// policy projections: P (fp32, N x 128) = A[N,128] @ B[128,128]
__launch_bounds__(256)
__global__ void k_gemm_pol(const float* __restrict__ A, const unsigned short* __restrict__ Bf,
                           float* __restrict__ P)
{
    int wave = threadIdx.x >> 6, lane = threadIdx.x & 63;
    int row0 = blockIdx.x * 64 + wave * 16;
    int arow = row0 + (lane & 15);
    int kb = (lane >> 4) * 8;
    bf16x8 af[4];
    load_afrag(A, arow, kb, af);
    int crow = row0 + (lane >> 4) * 4;
    int c0 = lane & 15;
#pragma unroll
    for (int ct = 0; ct < 8; ct++) {
        f32x4 acc = {0.f, 0.f, 0.f, 0.f};
#pragma unroll
        for (int kt = 0; kt < 4; kt++) {
            bf16x8 bf = *reinterpret_cast<const bf16x8*>(Bf + ((size_t)(kt * 8 + ct) * 64 + lane) * 8);
            acc = __builtin_amdgcn_mfma_f32_16x16x32_bf16(af[kt], bf, acc, 0, 0, 0);
        }
        int col = ct * 16 + c0;
#pragma unroll
        for (int r = 0; r < 4; r++)
            P[(size_t)(crow + r) * 128 + col] = acc[r];
    }
}

// ---------------- GATv2 edge aggregation ----------------
// one wave per 8 consecutive dst nodes; lane l owns features 2l,2l+1 (head = l>>4);
// online softmax per head; 2-edge unroll; xl/xr bf16; edge attrs bf16 in CSR order.

__launch_bounds__(256)
__global__ void k_gat(const unsigned short* __restrict__ xlb, const unsigned short* __restrict__ xrb,
                      const unsigned short* __restrict__ eaCSR,
                      const int* __restrict__ rowptr, const int* __restrict__ csr_src,
                      const float* __restrict__ We, const float* __restrict__ att,
                      const float* __restrict__ bconv, float* __restrict__ g)
{
    int wid = blockIdx.x * 4 + (threadIdx.x >> 6);   // 8192 waves, 8 nodes each
    int lane = threadIdx.x & 63;
    int f0 = lane * 2;

    float wex[12], wey[12];
#pragma unroll
    for (int k = 0; k < 12; k++) {
        float2 w = *reinterpret_cast<const float2*>(We + k * 128 + f0);
        wex[k] = w.x; wey[k] = w.y;
    }
    float2 av = *reinterpret_cast<const float2*>(att + f0);
    float2 bc = *reinterpret_cast<const float2*>(bconv + f0);

    for (int n = wid * 8; n < wid * 8 + 8; ++n) {
        unsigned int xrw = *reinterpret_cast<const unsigned int*>(xrb + (size_t)n * 128 + f0);
        float xr0 = bflo(xrw), xr1 = bfhi(xrw);

        float m = -INFINITY, s = 0.f, a0 = 0.f, a1 = 0.f;
        int beg = rowptr[n], end = rowptr[n + 1];
        int idx = beg;
        for (; idx + 2 <= end; idx += 2) {
            int s0 = csr_src[idx], s1 = csr_src[idx + 1];
            const uint2* q0 = reinterpret_cast<const uint2*>(eaCSR + (size_t)idx * 12);
            uint2 qa = q0[0], qb = q0[1], qc = q0[2];
            uint2 ra = q0[3], rb = q0[4], rc = q0[5];
            unsigned int xw0 = *reinterpret_cast<const unsigned int*>(xlb + (size_t)s0 * 128 + f0);
            unsigned int xw1 = *reinterpret_cast<const unsigned int*>(xlb + (size_t)s1 * 128 + f0);

            float e0[12], e1[12];
            e0[0] = bflo(qa.x); e0[1] = bfhi(qa.x); e0[2]  = bflo(qa.y); e0[3]  = bfhi(qa.y);
            e0[4] = bflo(qb.x); e0[5] = bfhi(qb.x); e0[6]  = bflo(qb.y); e0[7]  = bfhi(qb.y);
            e0[8] = bflo(qc.x); e0[9] = bfhi(qc.x); e0[10] = bflo(qc.y); e0[11] = bfhi(qc.y);
            e1[0] = bflo(ra.x); e1[1] = bfhi(ra.x); e1[2]  = bflo(ra.y); e1[3]  = bfhi(ra.y);
            e1[4] = bflo(rb.x); e1[5] = bfhi(rb.x); e1[6]  = bflo(rb.y); e1[7]  = bfhi(rb.y);
            e1[8] = bflo(rc.x); e1[9] = bfhi(rc.x); e1[10] = bflo(rc.y); e1[11] = bfhi(rc.y);

            float ex0 = 0.f, ey0 = 0.f, ex1 = 0.f, ey1 = 0.f;
#pragma unroll
            for (int k = 0; k < 12; k++) {
                ex0 = fmaf(e0[k], wex[k], ex0); ey0 = fmaf(e0[k], wey[k], ey0);
                ex1 = fmaf(e1[k], wex[k], ex1); ey1 = fmaf(e1[k], wey[k], ey1);
            }
            float xa0 = bflo(xw0), xa1 = bfhi(xw0);
            float xb0 = bflo(xw1), xb1 = bfhi(xw1);

            float m00 = xa0 + xr0 + ex0, m01 = xa1 + xr1 + ey0;
            float m10 = xb0 + xr0 + ex1, m11 = xb1 + xr1 + ey1;
            float v00 = (m00 > 0.f) ? m00 : 0.2f * m00;
            float v01 = (m01 > 0.f) ? m01 : 0.2f * m01;
            float v10 = (m10 > 0.f) ? m10 : 0.2f * m10;
            float v11 = (m11 > 0.f) ? m11 : 0.2f * m11;
            float t0 = v00 * av.x + v01 * av.y;
            float t1 = v10 * av.x + v11 * av.y;
            t0 += __shfl_xor(t0, 1);  t1 += __shfl_xor(t1, 1);
            t0 += __shfl_xor(t0, 2);  t1 += __shfl_xor(t1, 2);
            t0 += __shfl_xor(t0, 4);  t1 += __shfl_xor(t1, 4);
            t0 += __shfl_xor(t0, 8);  t1 += __shfl_xor(t1, 8);

            float nm = fmaxf(m, fmaxf(t0, t1));
            float so = __expf(m - nm);
            float w0 = __expf(t0 - nm);
            float w1 = __expf(t1 - nm);
            s  = s * so + w0 + w1;
            a0 = a0 * so + w0 * xa0 + w1 * xb0;
            a1 = a1 * so + w0 * xa1 + w1 * xb1;
            m = nm;
        }
        if (idx < end) {
            int s0 = csr_src[idx];
            const uint2* q0 = reinterpret_cast<const uint2*>(eaCSR + (size_t)idx * 12);
            uint2 qa = q0[0], qb = q0[1], qc = q0[2];
            unsigned int xw0 = *reinterpret_cast<const unsigned int*>(xlb + (size_t)s0 * 128 + f0);
            float e0[12];
            e0[0] = bflo(qa.x); e0[1] = bfhi(qa.x); e0[2]  = bflo(qa.y); e0[3]  = bfhi(qa.y);
            e0[4] = bflo(qb.x); e0[5] = bfhi(qb.x); e0[6]  = bflo(qb.y); e0[7]  = bfhi(qb.y);
            e0[8] = bflo(qc.x); e0[9] = bfhi(qc.x); e0[10] = bflo(qc.y); e0[11] = bfhi(qc.y);
            float ex0 = 0.f, ey0 = 0.f;
#pragma unroll
            for (int k = 0; k < 12; k++) {
                ex0 = fmaf(e0[k], wex[k], ex0); ey0 = fmaf(e0[k], wey[k], ey0);
            }
            float xa0 = bflo(xw0), xa1 = bfhi(xw0);
            float m0 = xa0 + xr0 + ex0;
            float m1 = xa1 + xr1 + ey0;
            float v0 = (m0 > 0.f) ? m0 : 0.2f * m0;
            float v1 = (m1 > 0.f) ? m1 : 0.2f * m1;
            float tt = v0 * av.x + v1 * av.y;
            tt += __shfl_xor(tt, 1);
            tt += __shfl_xor(tt, 2);
            tt += __shfl_xor(tt, 4);
            tt += __shfl_xor(tt, 8);
            float nm = fmaxf(m, tt);
            float so = __expf(m - nm);
            float w  = __expf(tt - nm);
            s  = s * so + w;
            a0 = a0 * so + w * xa0;
            a1 = a1 * so + w * xa1;
            m = nm;
        }
        float inv = 1.f / s;   // s > 0 guaranteed by the self-loop
        float2 r; r.x = a0 * inv + bc.x; r.y = a1 * inv + bc.y;
        *reinterpret_cast<float2*>(g + (size_t)n * 128 + f0) = r;
    }
}

// ---------------- BatchNorm ----------------

__launch_bounds__(256)
__global__ void k_bnstats(const float* __restrict__ X, float* __restrict__ sum, float* __restrict__ sq)
{
    int col = threadIdx.x & 127;
    int half = threadIdx.x >> 7;
    int rbase = blockIdx.x * 256 + half;
    float s = 0.f, q = 0.f;
    for (int i = 0; i < 128; i++) {
        float v = X[(size_t)(rbase + i * 2) * 128 + col];
        s += v; q += v * v;
    }
    __shared__ float ls[256], lq[256];
    ls[threadIdx.x] = s; lq[threadIdx.x] = q;
    __syncthreads();
    if (half == 0) {
        s += ls[threadIdx.x + 128];
        q += lq[threadIdx.x + 128];
        atomicAdd(&sum[col], s);
        atomicAdd(&sq[col], q);
    }
}

__device__ __forceinline__ void bn_coeffs(const float* __restrict__ bnsum, const float* __restrict__ bnsq,
                                          const float* __restrict__ scale, const float* __restrict__ bias,
                                          float* sA, float* bA)
{
    int t = threadIdx.x;
    if (t < 128) {
        const float invN = 1.0f / (float)NN;
        float mean = bnsum[t] * invN;
        float var  = bnsq[t] * invN - mean * mean;
        float sc   = scale[t] * rsqrtf(var + 1e-5f);
        sA[t] = sc;
        bA[t] = bias[t] - mean * sc;
    }
    __syncthreads();
}

__launch_bounds__(256)
__global__ void k_bnapply_relu(const float4* __restrict__ gin,
                               const float* __restrict__ bnsum, const float* __restrict__ bnsq,
                               const float* __restrict__ scale, const float* __restrict__ bias,
                               float4* __restrict__ out)
{
    __shared__ float sA[128], bA[128];
    bn_coeffs(bnsum, bnsq, scale, bias, sA, bA);
    int idx = blockIdx.x * 256 + threadIdx.x;   // NN*128/4 threads
    int c4 = (idx & 31) * 4;
    float4 v = gin[idx];
    float4 r;
    r.x = fmaxf(fmaf(v.x, sA[c4 + 0], bA[c4 + 0]), 0.f);
    r.y = fmaxf(fmaf(v.y, sA[c4 + 1], bA[c4 + 1]), 0.f);
    r.z = fmaxf(fmaf(v.z, sA[c4 + 2], bA[c4 + 2]), 0.f);
    r.w = fmaxf(fmaf(v.w, sA[c4 + 3], bA[c4 + 3]), 0.f);
    out[idx] = r;
}

__launch_bounds__(256)
__global__ void k_bnapply_res_relu(const float4* __restrict__ gin,
                                   const float* __restrict__ bnsum, const float* __restrict__ bnsq,
                                   const float* __restrict__ scale, const float* __restrict__ bias,
                                   float4* __restrict__ hbuf)
{
    __shared__ float sA[128], bA[128];
    bn_coeffs(bnsum, bnsq, scale, bias, sA, bA);
    int idx = blockIdx.x * 256 + threadIdx.x;
    int c4 = (idx & 31) * 4;
    float4 v = gin[idx];
    float4 hv = hbuf[idx];
    float4 r;
    r.x = fmaxf(fmaf(v.x, sA[c4 + 0], bA[c4 + 0]) + hv.x, 0.f);
    r.y = fmaxf(fmaf(v.y, sA[c4 + 1], bA[c4 + 1]) + hv.y, 0.f);
    r.z = fmaxf(fmaf(v.z, sA[c4 + 2], bA[c4 + 2]) + hv.z, 0.f);
    r.w = fmaxf(fmaf(v.w, sA[c4 + 3], bA[c4 + 3]) + hv.w, 0.f);
    hbuf[idx] = r;
}

// ---------------- pooling + value head ----------------

__launch_bounds__(128)
__global__ void k_pool(const float* __restrict__ h, const int* __restrict__ batch,
                       float* __restrict__ pooled, float* __restrict__ cnt)
{
    int c = threadIdx.x;
    int r0 = blockIdx.x * 128;
    int cur = batch[r0];
    float acc = 0.f;
    float run = 0.f;
    for (int i = 0; i < 128; ++i) {
        int r = r0 + i;
        int b = batch[r];
        if (b != cur) {
            atomicAdd(&pooled[(size_t)cur * 128 + c], acc);
            if (c == 0) atomicAdd(&cnt[cur], run);
            acc = 0.f; run = 0.f; cur = b;
        }
        acc += h[(size_t)r * 128 + c];
        run += 1.f;
    }
    atomicAdd(&pooled[(size_t)cur * 128 + c], acc);
    if (c == 0) atomicAdd(&cnt[cur], run);
}

__launch_bounds__(64)
__global__ void k_value(const float* __restrict__ pooled, const float* __restrict__ cnt,
                        const float* __restrict__ Wv1, const float* __restrict__ bv1,
                        const float* __restrict__ Wv2, const float* __restrict__ bv2,
                        float* __restrict__ out)
{
    int gi = blockIdx.x;
    int l = threadIdx.x;
    float inv = 1.f / fmaxf(cnt[gi], 1.f);
    const float* pr = pooled + (size_t)gi * 128;
    float z = bv1[l];
    for (int k = 0; k < 128; k++) z = fmaf(pr[k] * inv, Wv1[k * 64 + l], z);
    z = fmaxf(z, 0.f);
#pragma unroll
    for (int j = 0; j < 3; j++) {
        float p = z * Wv2[l * 3 + j];
        p += __shfl_xor(p, 32); p += __shfl_xor(p, 16); p += __shfl_xor(p, 8);
        p += __shfl_xor(p, 4);  p += __shfl_xor(p, 2);  p += __shfl_xor(p, 1);
        if (l == 0) out[gi * 3 + j] = p + bv2[j];
    }
}

// ---------------- policy head ----------------
// policy[e] = relu(P[src][0:64] + P[dst][64:128] + ea@Wp1c + bp1) . Wp2 + bp2

__launch_bounds__(256)
__global__ void k_policy(const float* __restrict__ P,
                         const float* __restrict__ eattr,
                         const int* __restrict__ src0, const int* __restrict__ dst0,
                         const float* __restrict__ Wp1c, const float* __restrict__ bp1,
                         const float* __restrict__ Wp2, const float* __restrict__ bp2,
                         float* __restrict__ out)
{
    int wave = (blockIdx.x * 256 + threadIdx.x) >> 6;   // 16384 waves
    int lane = threadIdx.x & 63;
    float w1c[12];
#pragma unroll
    for (int k = 0; k < 12; k++) w1c[k] = Wp1c[k * 64 + lane];
    float wp2 = Wp2[lane];
    float bb = bp1[lane];
    float b2 = bp2[0];
    for (int i = 0; i < 8; i++) {
        int e = wave * 8 + i;
        int sI = src0[e], dI = dst0[e];
        const float* ep = eattr + (size_t)e * 12;
        float4 e0 = *reinterpret_cast<const float4*>(ep);
        float4 e1 = *reinterpret_cast<const float4*>(ep + 4);
        float4 e2 = *reinterpret_cast<const float4*>(ep + 8);
        float z = P[(size_t)sI * 128 + lane] + P[(size_t)dI * 128 + 64 + lane] + bb;
        z += e0.x * w1c[0] + e0.y * w1c[1] + e0.z * w1c[2]  + e0.w * w1c[3]
           + e1.x * w1c[4] + e1.y * w1c[5] + e1.z * w1c[6]  + e1.w * w1c[7]
           + e2.x * w1c[8] + e2.y * w1c[9] + e2.z * w1c[10] + e2.w * w1c[11];
        z = fmaxf(z, 0.f);
        float p = z * wp2;
        p += __shfl_xor(p, 32); p += __shfl_xor(p, 16); p += __shfl_xor(p, 8);
        p += __shfl_xor(p, 4);  p += __shfl_xor(p, 2);  p += __shfl_xor(p, 1);
        if (lane == 0) out[3072 + e] = p + b2;
    }
}

// ---------------- host ----------------

extern "C" void kernel_launch(void* const* d_in, const int* in_sizes, int n_in,
                              void* d_out, int out_size, void* d_ws, size_t ws_size,
                              hipStream_t stream)
{
    const float* x     = (const float*)d_in[0];
    const float* eattr = (const float*)d_in[1];
    const int*   eidx  = (const int*)d_in[2];
    const int*   batch = (const int*)d_in[3];
    const float* Win   = (const float*)d_in[4];
    const float* bin   = (const float*)d_in[5];
    const float* Wl    = (const float*)d_in[6];
    const float* Wr    = (const float*)d_in[7];
    const float* We    = (const float*)d_in[8];
    const float* att   = (const float*)d_in[9];
    const float* bconv = (const float*)d_in[10];
    const float* bnsc  = (const float*)d_in[11];
    const float* bnbi  = (const float*)d_in[12];
    const float* Wv1   = (const float*)d_in[13];
    const float* bv1   = (const float*)d_in[14];
    const float* Wv2   = (const float*)d_in[15];
    const float* bv2   = (const float*)d_in[16];
    const float* Wp1   = (const float*)d_in[17];
    const float* bp1   = (const float*)d_in[18];
    const float* Wp2   = (const float*)d_in[19];
    const float* bp2   = (const float*)d_in[20];
    float* out = (float*)d_out;

    const int* src0 = eidx;
    const int* dst0 = eidx + EE;

    const size_t NH = (size_t)NN * 128;
    float* ws = (float*)d_ws;
    float* h  = ws;                    // N*128 fp32
    float* h1 = h + NH;                // N*128 fp32
    float* g  = h1 + NH;               // N*128 fp32 (reused as P for policy head)
    unsigned short* xlb = (unsigned short*)(g + NH);        // N*128 bf16
    unsigned short* xrb = xlb + NH;                          // N*128 bf16
    unsigned short* eaCSR = xrb + NH;                        // EPX*12 bf16
    int* rowptr = (int*)(eaCSR + (size_t)EPX * 12);          // N+1
    int* csr_src = rowptr + (NN + 1);                        // EPX
    // --- zeroed region (one memset) ---
    int* deg  = csr_src + EPX;         // N
    int* fill = deg + NN;              // N
    float* bnstat = (float*)(fill + NN);        // 8 layers * 256 (sum|sq)
    float* pooled = bnstat + 8 * 256;           // G*128
    float* cnt    = pooled + (size_t)GG * 128;  // G
    size_t zero_elems = (size_t)NN + NN + 8 * 256 + (size_t)GG * 128 + GG;
    // --- MFMA-swizzled weights (fully rewritten each launch) ---
    unsigned short* wg = (unsigned short*)(cnt + GG);   // 8*32768
    unsigned short* wp = wg + 8 * 32768;                // 16384

    hipMemsetAsync(deg, 0, zero_elems * sizeof(float), stream);

    // CSR build + weight prep
    k_deg<<<EE / 256, 256, 0, stream>>>(dst0, deg);
    k_scan<<<1, 1024, 0, stream>>>(deg, rowptr);
    k_scatter<<<EPX / 256, 256, 0, stream>>>(src0, dst0, eattr, rowptr, deg, fill, csr_src, eaCSR);
    k_selfattr<<<(NN * 16) / 256, 256, 0, stream>>>(rowptr, eaCSR);
    k_wprep<<<136, 256, 0, stream>>>(Wl, Wr, Wp1, wg, wp);

    // input layer
    k_input<<<NN / 16, 256, 0, stream>>>(x, Win, bin, h);

    // 8 GATv2 + BN layers
    for (int l = 0; l < 8; l++) {
        const float* hin = (l % 2 == 0) ? h : h1;
        float* bs = bnstat + l * 256;
        k_gemm_gat<<<NN / 64, 256, 0, stream>>>(hin, wg + (size_t)l * 32768, xlb, xrb);
        k_gat<<<NN / 32, 256, 0, stream>>>(xlb, xrb, eaCSR, rowptr, csr_src,
                                           We + (size_t)l * 1536, att + (size_t)l * 128,
                                           bconv + (size_t)l * 128, g);
        k_bnstats<<<256, 256, 0, stream>>>(g, bs, bs + 128);
        if (l % 2 == 0)
            k_bnapply_relu<<<(NN * 128 / 4) / 256, 256, 0, stream>>>(
                (const float4*)g, bs, bs + 128, bnsc + (size_t)l * 128, bnbi + (size_t)l * 128,
                (float4*)h1);
        else
            k_bnapply_res_relu<<<(NN * 128 / 4) / 256, 256, 0, stream>>>(
                (const float4*)g, bs, bs + 128, bnsc + (size_t)l * 128, bnbi + (size_t)l * 128,
                (float4*)h);
    }

    // pooling + value head
    k_pool<<<NN / 128, 128, 0, stream>>>(h, batch, pooled, cnt);
    k_value<<<GG, 64, 0, stream>>>(pooled, cnt, Wv1, bv1, Wv2, bv2, out);

    // policy head
    float* P = g;
    k_gemm_pol<<<NN / 64, 256, 0, stream>>>(h, wp, P);
    k_policy<<<NN / 4, 256, 0, stream>>>(P, eattr, src0, dst0,
                                         Wp1 + 256 * 64, bp1, Wp2, bp2, out);
}